// Round 3
// baseline (1005.463 us; speedup 1.0000x reference)
//
#include <hip/hip_runtime.h>

// CapsuleLayer fused pipeline, round 3.
//  - Routing fp32-exact (k_upd in-place softmax, LDS 34K -> 4 blocks/CU;
//    k_sow/k_fwv 32-b chunks, grid 1024, 4 blocks/CU).
//  - ssq via bf16 MFMA (k_ih, unchanged from R2).
//  - k_prep: A_h = Wq_h.Wk_h^T and symmetric pair-matrix K from kmf, written
//    into the xc region (dead after k_fwv).
//  - k_attn replaces k_int+k_fm: per-b fused S=fwv.A.fwv^T -> softmax ->
//    P.(fwv.Wv) + fwv.Wr -> relu/khi reduce, plus FM and MF (=0.5*fw^T K fw).
//    LDS 38.25 KB via bf16 staging + half-matrix staging + buffer unions ->
//    4 blocks/CU, entire grid co-resident.

#define EPS_SQ 1e-7f

typedef __attribute__((ext_vector_type(8))) short bf16x8;
typedef __attribute__((ext_vector_type(4))) float floatx4;

__device__ __forceinline__ int lidx(int r, int c) {
  // 64-col fp32 tile, row stride 68 dwords, quad-swizzle
  return r * 68 + ((((c >> 2) ^ (r >> 2)) & 15) << 2) + (c & 3);
}
__device__ __forceinline__ unsigned short f2bf(float f) {
  unsigned u = __float_as_uint(f);
  u += 0x7FFFu + ((u >> 16) & 1u);   // RNE
  return (unsigned short)(u >> 16);
}
__device__ __forceinline__ unsigned pack2(float a, float b) {
  return (unsigned)f2bf(a) | ((unsigned)f2bf(b) << 16);
}
__device__ __forceinline__ void unpack8(const unsigned short* p, float* o) {
  uint4 u = *(const uint4*)p;
  o[0] = __uint_as_float(u.x << 16); o[1] = __uint_as_float(u.x & 0xFFFF0000u);
  o[2] = __uint_as_float(u.y << 16); o[3] = __uint_as_float(u.y & 0xFFFF0000u);
  o[4] = __uint_as_float(u.z << 16); o[5] = __uint_as_float(u.z & 0xFFFF0000u);
  o[6] = __uint_as_float(u.w << 16); o[7] = __uint_as_float(u.w & 0xFFFF0000u);
}

// ---------------------------------------------------------------------------
// k_upd(iter): [iter>0] blog += x . ow^T ; softmax over capsules (in place in
// bS); xc = c . x ; [iter==3] write routing_score. One block per b.
// ---------------------------------------------------------------------------
__global__ __launch_bounds__(256) void k_upd(
    const float* __restrict__ x, const float* __restrict__ rinit,
    const float* __restrict__ ow, float* __restrict__ blog,
    float* __restrict__ xc, float* __restrict__ rs, int iter)
{
  __shared__ __align__(16) float xs[64 * 68];
  __shared__ __align__(16) float owS[32 * 68];
  __shared__ __align__(16) float bS[32 * 68];   // logits, then softmax in place
  const int b = blockIdx.x, t = threadIdx.x;
  const float* xb = x + b * 4096;

#pragma unroll
  for (int k = 0; k < 4; k++) {
    int lin = t + 256 * k; int f = lin >> 4; int d0 = (lin & 15) << 2;
    *(float4*)&xs[lidx(f, d0)] = *(const float4*)(xb + f * 64 + d0);
  }
  {
    const float* src = (iter <= 1) ? rinit : (blog + b * 2048);
#pragma unroll
    for (int k = 0; k < 2; k++) {
      int lin = t + 256 * k; int n = lin >> 4; int f0 = (lin & 15) << 2;
      *(float4*)&bS[lidx(n, f0)] = *(const float4*)(src + n * 64 + f0);
    }
  }
  if (iter > 0) {
#pragma unroll
    for (int k = 0; k < 2; k++) {
      int lin = t + 256 * k; int n = lin >> 4; int d0 = (lin & 15) << 2;
      *(float4*)&owS[lidx(n, d0)] = *(const float4*)(ow + b * 2048 + n * 64 + d0);
    }
  }
  __syncthreads();

  const int tn = t >> 4, tlo = t & 15;

  if (iter > 0) {
    const int n0 = tn * 2, f0 = tlo * 4;
    float acc[2][4] = {{0, 0, 0, 0}, {0, 0, 0, 0}};
    for (int dq = 0; dq < 64; dq += 4) {
      float o[2][4];
      *(float4*)o[0] = *(const float4*)&owS[lidx(n0, dq)];
      *(float4*)o[1] = *(const float4*)&owS[lidx(n0 + 1, dq)];
#pragma unroll
      for (int i = 0; i < 4; i++) {
        float xr[4];
        *(float4*)xr = *(const float4*)&xs[lidx(f0 + i, dq)];
#pragma unroll
        for (int k = 0; k < 4; k++) {
          acc[0][i] += o[0][k] * xr[k];
          acc[1][i] += o[1][k] * xr[k];
        }
      }
    }
#pragma unroll
    for (int j = 0; j < 2; j++) {
      float tmp[4];
      *(float4*)tmp = *(const float4*)&bS[lidx(n0 + j, f0)];
#pragma unroll
      for (int i = 0; i < 4; i++) tmp[i] += acc[j][i];
      *(float4*)&bS[lidx(n0 + j, f0)] = *(float4*)tmp;
    }
    __syncthreads();
    if (iter < 3) {
#pragma unroll
      for (int k = 0; k < 2; k++) {
        int lin = t + 256 * k; int n = lin >> 4; int f0b = (lin & 15) << 2;
        *(float4*)(blog + b * 2048 + n * 64 + f0b) = *(const float4*)&bS[lidx(n, f0b)];
      }
    }
    __syncthreads();  // writeback readers done before in-place softmax
  }

  // softmax over n per f column, in place in bS
  {
    const int n = t & 31, fg = t >> 5;
#pragma unroll
    for (int k = 0; k < 8; k++) {
      int f = fg * 8 + k;
      float v = bS[lidx(n, f)];
      float m = v;
      for (int s = 16; s > 0; s >>= 1) m = fmaxf(m, __shfl_xor(m, s, 64));
      float e = __expf(v - m);
      float sum = e;
      for (int s = 16; s > 0; s >>= 1) sum += __shfl_xor(sum, s, 64);
      bS[lidx(n, f)] = e / sum;
    }
  }
  __syncthreads();

  if (iter == 3) {
#pragma unroll
    for (int k = 0; k < 8; k++) {
      int lin = t + 256 * k; int n = lin >> 6, f = lin & 63;
      rs[b * 2048 + n * 64 + f] = bS[lidx(n, f)];
    }
  }
  // xc[n,d] = sum_f c[n,f]*x[f,d]
  {
    const int n0 = tn * 2, d0 = tlo * 4;
    float acc[2][4] = {{0, 0, 0, 0}, {0, 0, 0, 0}};
    for (int f = 0; f < 64; f++) {
      float c0v = bS[lidx(n0, f)];
      float c1v = bS[lidx(n0 + 1, f)];
      float xr[4];
      *(float4*)xr = *(const float4*)&xs[lidx(f, d0)];
#pragma unroll
      for (int i = 0; i < 4; i++) {
        acc[0][i] += c0v * xr[i];
        acc[1][i] += c1v * xr[i];
      }
    }
#pragma unroll
    for (int j = 0; j < 2; j++)
      *(float4*)(xc + b * 2048 + (n0 + j) * 64 + d0) = *(float4*)acc[j];
  }
}

// ---------------------------------------------------------------------------
// k_sow: per (n, 32-b chunk): s = xc.Mn ; o = squash(s) ; ow = Mn.o. grid 1024.
// ---------------------------------------------------------------------------
__global__ __launch_bounds__(256) void k_sow(
    const float* __restrict__ W, const float* __restrict__ xc,
    float* __restrict__ ow)
{
  __shared__ __align__(16) float Mn[64 * 68];
  __shared__ __align__(16) float xcS[32 * 68];
  __shared__ __align__(16) float sS[32 * 68];
  __shared__ float scaleS[32];
  const int n = blockIdx.x & 31, b0 = (blockIdx.x >> 5) * 32, t = threadIdx.x;

#pragma unroll
  for (int k = 0; k < 4; k++) {
    int lin = t + 256 * k; int d = lin >> 4; int c0 = (lin & 15) << 2;
    *(float4*)&Mn[lidx(d, c0)] = *(const float4*)(W + d * 2048 + n * 64 + c0);
  }
#pragma unroll
  for (int k = 0; k < 2; k++) {
    int lin = t + 256 * k; int bb = lin >> 4; int d0 = (lin & 15) << 2;
    *(float4*)&xcS[lidx(bb, d0)] = *(const float4*)(xc + (b0 + bb) * 2048 + n * 64 + d0);
  }
  __syncthreads();

  const int bb0 = (t >> 4) * 2, c4 = (t & 15) * 4;
  {
    float acc[2][4] = {};
    for (int dq = 0; dq < 64; dq += 4) {
      float xv0[4], xv1[4];
      *(float4*)xv0 = *(const float4*)&xcS[lidx(bb0, dq)];
      *(float4*)xv1 = *(const float4*)&xcS[lidx(bb0 + 1, dq)];
#pragma unroll
      for (int j = 0; j < 4; j++) {
        float mr[4];
        *(float4*)mr = *(const float4*)&Mn[lidx(dq + j, c4)];
#pragma unroll
        for (int c = 0; c < 4; c++) {
          acc[0][c] += xv0[j] * mr[c];
          acc[1][c] += xv1[j] * mr[c];
        }
      }
    }
    *(float4*)&sS[lidx(bb0, c4)] = *(float4*)acc[0];
    *(float4*)&sS[lidx(bb0 + 1, c4)] = *(float4*)acc[1];
  }
  __syncthreads();
  if (t < 32) {
    float ss = EPS_SQ;
    for (int c = 0; c < 64; c++) { float v = sS[lidx(t, c)]; ss += v * v; }
    scaleS[t] = sqrtf(ss) / (0.5f + ss);
  }
  __syncthreads();
  {
    float a2[2][4] = {};
    for (int cq = 0; cq < 64; cq += 4) {
      float sv0[4], sv1[4];
      *(float4*)sv0 = *(const float4*)&sS[lidx(bb0, cq)];
      *(float4*)sv1 = *(const float4*)&sS[lidx(bb0 + 1, cq)];
#pragma unroll
      for (int j = 0; j < 4; j++) {
        float mr[4];
        *(float4*)mr = *(const float4*)&Mn[lidx(c4 + j, cq)];
        float s0 = 0.f, s1 = 0.f;
#pragma unroll
        for (int k = 0; k < 4; k++) { s0 += sv0[k] * mr[k]; s1 += sv1[k] * mr[k]; }
        a2[0][j] += s0; a2[1][j] += s1;
      }
    }
#pragma unroll
    for (int i = 0; i < 2; i++) {
      float sc = scaleS[bb0 + i];
      float outv[4];
#pragma unroll
      for (int j = 0; j < 4; j++) outv[j] = a2[i][j] * sc;
      *(float4*)(ow + (b0 + bb0 + i) * 2048 + n * 64 + c4) = *(float4*)outv;
    }
  }
}

// ---------------------------------------------------------------------------
// k_fwv: fwv = xc_final . W (exact fp32), per (n, 32-b chunk). grid 1024.
// ---------------------------------------------------------------------------
__global__ __launch_bounds__(256) void k_fwv(
    const float* __restrict__ W, const float* __restrict__ xc,
    float* __restrict__ fwv)
{
  __shared__ __align__(16) float Mn[64 * 68];
  __shared__ __align__(16) float xcS[32 * 68];
  const int n = blockIdx.x & 31, b0 = (blockIdx.x >> 5) * 32, t = threadIdx.x;

#pragma unroll
  for (int k = 0; k < 4; k++) {
    int lin = t + 256 * k; int d = lin >> 4; int c0 = (lin & 15) << 2;
    *(float4*)&Mn[lidx(d, c0)] = *(const float4*)(W + d * 2048 + n * 64 + c0);
  }
#pragma unroll
  for (int k = 0; k < 2; k++) {
    int lin = t + 256 * k; int bb = lin >> 4; int d0 = (lin & 15) << 2;
    *(float4*)&xcS[lidx(bb, d0)] = *(const float4*)(xc + (b0 + bb) * 2048 + n * 64 + d0);
  }
  __syncthreads();

  const int bb0 = (t >> 4) * 2, c4 = (t & 15) * 4;
  float acc[2][4] = {};
  for (int dq = 0; dq < 64; dq += 4) {
    float xv0[4], xv1[4];
    *(float4*)xv0 = *(const float4*)&xcS[lidx(bb0, dq)];
    *(float4*)xv1 = *(const float4*)&xcS[lidx(bb0 + 1, dq)];
#pragma unroll
    for (int j = 0; j < 4; j++) {
      float mr[4];
      *(float4*)mr = *(const float4*)&Mn[lidx(dq + j, c4)];
#pragma unroll
      for (int c = 0; c < 4; c++) {
        acc[0][c] += xv0[j] * mr[c];
        acc[1][c] += xv1[j] * mr[c];
      }
    }
  }
  *(float4*)(fwv + (b0 + bb0) * 2048 + n * 64 + c4) = *(float4*)acc[0];
  *(float4*)(fwv + (b0 + bb0 + 1) * 2048 + n * 64 + c4) = *(float4*)acc[1];
}

// ---------------------------------------------------------------------------
// k_ih: ssq[b,n,c] = sum_f (c[n,f]*ih[b,n,f,c])^2 via bf16 MFMA (unchanged R2).
// ---------------------------------------------------------------------------
__global__ __launch_bounds__(256) void k_ih(
    const float* __restrict__ x, const float* __restrict__ W,
    const float* __restrict__ rs, float* __restrict__ ssq)
{
  __shared__ __align__(16) unsigned short xB[4 * 64 * 64];
  __shared__ __align__(16) unsigned short wB[2 * 64 * 64];
  __shared__ float cF2[4 * 2 * 64];
  const int n0 = (blockIdx.x & 15) * 2, g = blockIdx.x >> 4;
  const int b0 = g * 4;
  const int t = threadIdx.x, w = t >> 6, lane = t & 63;

#pragma unroll
  for (int k = 0; k < 16; k++) {
    int ch = t + 256 * k;
    int bb = ch >> 10, rem = ch & 1023;
    int f = rem >> 4, fq = rem & 15;
    int dg = fq >> 1, half = fq & 1;
    float4 v = *(const float4*)(x + ((b0 + bb) * 64 + f) * 64 + fq * 4);
    unsigned int p0 = f2bf(v.x) | ((unsigned)f2bf(v.y) << 16);
    unsigned int p1 = f2bf(v.z) | ((unsigned)f2bf(v.w) << 16);
    *(uint2*)&xB[bb * 4096 + f * 64 + ((dg ^ (f & 7)) << 3) + half * 4] =
        make_uint2(p0, p1);
  }
  {
    int dd = t >> 2, cq = t & 3;
    int dg = dd >> 3, dl = dd & 7;
#pragma unroll
    for (int nn = 0; nn < 2; nn++) {
      const float* wp = W + dd * 2048 + (n0 + nn) * 64 + cq * 16;
      unsigned short* base = wB + nn * 4096;
#pragma unroll
      for (int i4 = 0; i4 < 4; i4++) {
        float4 v = *(const float4*)(wp + i4 * 4);
        float vv[4] = {v.x, v.y, v.z, v.w};
#pragma unroll
        for (int j = 0; j < 4; j++) {
          int c = cq * 16 + i4 * 4 + j;
          base[c * 64 + ((dg ^ (c & 7)) << 3) + dl] = f2bf(vv[j]);
        }
      }
    }
  }
  {
#pragma unroll
    for (int nn = 0; nn < 2; nn++) {
      float v = rs[(b0 + w) * 2048 + (n0 + nn) * 64 + lane];
      cF2[(w * 2 + nn) * 64 + lane] = v * v;
    }
  }
  __syncthreads();

  const int m = lane & 15, q = lane >> 4, ms = m & 7;

  bf16x8 a[4][2];
#pragma unroll
  for (int mi = 0; mi < 4; mi++) {
    const unsigned short* bp = xB + w * 4096 + (mi * 16 + m) * 64;
#pragma unroll
    for (int kk = 0; kk < 2; kk++)
      a[mi][kk] = *(const bf16x8*)&bp[((kk * 4 + q) ^ ms) << 3];
  }

#pragma unroll
  for (int nn = 0; nn < 2; nn++) {
    bf16x8 bf[4][2];
#pragma unroll
    for (int ci = 0; ci < 4; ci++) {
      const unsigned short* bp = wB + nn * 4096 + (ci * 16 + m) * 64;
#pragma unroll
      for (int kk = 0; kk < 2; kk++)
        bf[ci][kk] = *(const bf16x8*)&bp[((kk * 4 + q) ^ ms) << 3];
    }
    float ps[4] = {0.f, 0.f, 0.f, 0.f};
    const float* cf = cF2 + (w * 2 + nn) * 64 + q * 4;
#pragma unroll
    for (int mi = 0; mi < 4; mi++) {
      float cfv[4];
#pragma unroll
      for (int r = 0; r < 4; r++) cfv[r] = cf[mi * 16 + r];
#pragma unroll
      for (int ci = 0; ci < 4; ci++) {
        floatx4 c0 = {0.f, 0.f, 0.f, 0.f};
        c0 = __builtin_amdgcn_mfma_f32_16x16x32_bf16(a[mi][0], bf[ci][0], c0, 0, 0, 0);
        c0 = __builtin_amdgcn_mfma_f32_16x16x32_bf16(a[mi][1], bf[ci][1], c0, 0, 0, 0);
#pragma unroll
        for (int r = 0; r < 4; r++) { float tv = c0[r]; ps[ci] += cfv[r] * tv * tv; }
      }
    }
#pragma unroll
    for (int ci = 0; ci < 4; ci++) {
      ps[ci] += __shfl_xor(ps[ci], 16, 64);
      ps[ci] += __shfl_xor(ps[ci], 32, 64);
    }
    if (q == 0) {
#pragma unroll
      for (int ci = 0; ci < 4; ci++)
        ssq[(b0 + w) * 2048 + (n0 + nn) * 64 + ci * 16 + m] = ps[ci];
    }
  }
}

// ---------------------------------------------------------------------------
// k_prep: blocks 0..7: A_h = Wq_h . Wk_h^T (h=bid&1, 16-row group bid>>1).
//         block 8: symmetric pair matrix K[32][32] from kmf (triu order).
// ---------------------------------------------------------------------------
__global__ __launch_bounds__(256) void k_prep(
    const float* __restrict__ Wq, const float* __restrict__ Wk,
    const float* __restrict__ kmf, float* __restrict__ Ab, float* __restrict__ Kb)
{
  const int t = threadIdx.x;
  if (blockIdx.x < 8) {
    __shared__ __align__(16) float wkS[64 * 68];
    __shared__ __align__(16) float wqS[16 * 68];
    const int h = blockIdx.x & 1, rg = blockIdx.x >> 1;
#pragma unroll
    for (int k = 0; k < 4; k++) {
      int lin = t + 256 * k; int dp = lin >> 4; int e0 = (lin & 15) << 2;
      *(float4*)&wkS[lidx(dp, e0)] = *(const float4*)(Wk + dp * 128 + h * 64 + e0);
    }
    {
      int dl = t >> 4, e0 = (t & 15) << 2;
      *(float4*)&wqS[lidx(dl, e0)] = *(const float4*)(Wq + (rg * 16 + dl) * 128 + h * 64 + e0);
    }
    __syncthreads();
    const int dl = t >> 4, dp0 = (t & 15) << 2;
    float acc[4] = {};
    for (int e = 0; e < 64; e += 4) {
      float q4[4];
      *(float4*)q4 = *(const float4*)&wqS[lidx(dl, e)];
#pragma unroll
      for (int c = 0; c < 4; c++) {
        float mr[4];
        *(float4*)mr = *(const float4*)&wkS[lidx(dp0 + c, e)];
        acc[c] += q4[0] * mr[0] + q4[1] * mr[1] + q4[2] * mr[2] + q4[3] * mr[3];
      }
    }
    *(float4*)(Ab + h * 4096 + (rg * 16 + dl) * 64 + dp0) = *(float4*)acc;
  } else {
    __shared__ float Ks[1024];
    *(float4*)&Ks[t * 4] = make_float4(0.f, 0.f, 0.f, 0.f);
    __syncthreads();
    if (t < 248) {
#pragma unroll
      for (int j = 0; j < 2; j++) {
        int p = t * 2 + j;
        if (p < 496) {
          int l = 0, rem = p;
          while (rem >= 31 - l) { rem -= 31 - l; ++l; }
          int r = l + 1 + rem;
          float v = kmf[p];
          Ks[l * 32 + r] = v;
          Ks[r * 32 + l] = v;
        }
      }
    }
    __syncthreads();
    *(float4*)&Kb[t * 4] = *(const float4*)&Ks[t * 4];
  }
}

// ---------------------------------------------------------------------------
// k_attn: per-b fused attention + FM + MF + high_int. One block per b.
// LDS 38.25 KB -> 4 blocks/CU (whole grid co-resident).
// ---------------------------------------------------------------------------
__global__ __launch_bounds__(256, 4) void k_attn(
    const float* __restrict__ fwv, const float* __restrict__ ssq,
    const float* __restrict__ Ab, const float* __restrict__ Kb,
    const float* __restrict__ Wv, const float* __restrict__ Wr,
    const float* __restrict__ kfm, const float* __restrict__ bfm,
    const float* __restrict__ bmf, const float* __restrict__ khi,
    const float* __restrict__ bhi, float* __restrict__ out0)
{
  __shared__ __align__(16) unsigned char smem[39168];
  float* fwS = (float*)smem;                                   // 32x68 f32 (8704B)
  float* buf1f = (float*)(smem + 8704);                        // A-half f32 / red1
  unsigned short* buf1u = (unsigned short*)(smem + 8704);      // Wv/Wr-half bf16 32x136 (8704B)
  unsigned short* tSu = (unsigned short*)(smem + 17408);       // T bf16 32x72 (4608B)
  float* Kf = (float*)(smem + 17408);                          // K alias (4096B)
  unsigned short* vSu = (unsigned short*)(smem + 22016);       // v bf16 32x136 (8704B)
  float* pS = (float*)(smem + 30720);                          // scores/probs 64x33 (8448B)
  float* redH = (float*)(smem + 30720);                        // alias: 16x132 f32

  const int b = blockIdx.x, t = threadIdx.x;
  const int tn = t >> 4, te = t & 15;
  const int n0 = tn * 2, e0 = te * 8;

#pragma unroll
  for (int k = 0; k < 2; k++) {
    int lin = t + 256 * k; int nn = lin >> 4; int c0 = (lin & 15) << 2;
    *(float4*)&fwS[lidx(nn, c0)] = *(const float4*)(fwv + b * 2048 + nn * 64 + c0);
  }
  __syncthreads();

  // ---- scores: S_h = (fwS . A_h) . fwS^T, both heads into pS --------------
  for (int h = 0; h < 2; h++) {
    const int d0 = te * 4;
    float tacc[2][4] = {};
    for (int half = 0; half < 2; half++) {
#pragma unroll
      for (int k = 0; k < 2; k++) {
        int lin = t + 256 * k; int d = lin >> 4; int c0 = (lin & 15) << 2;
        *(float4*)&buf1f[lidx(d, c0)] =
            *(const float4*)(Ab + h * 4096 + (half * 32 + d) * 64 + c0);
      }
      __syncthreads();
      for (int dq = 0; dq < 32; dq += 4) {
        float fw0[4], fw1[4];
        *(float4*)fw0 = *(const float4*)&fwS[lidx(n0, half * 32 + dq)];
        *(float4*)fw1 = *(const float4*)&fwS[lidx(n0 + 1, half * 32 + dq)];
#pragma unroll
        for (int j = 0; j < 4; j++) {
          float mr[4];
          *(float4*)mr = *(const float4*)&buf1f[lidx(dq + j, d0)];
#pragma unroll
          for (int c = 0; c < 4; c++) {
            tacc[0][c] += fw0[j] * mr[c];
            tacc[1][c] += fw1[j] * mr[c];
          }
        }
      }
      __syncthreads();
    }
    // write T as bf16 (rows stride 72 ushorts = 144B; 8B-aligned uint2 writes)
#pragma unroll
    for (int i = 0; i < 2; i++) {
      uint2 pk = make_uint2(pack2(tacc[i][0], tacc[i][1]), pack2(tacc[i][2], tacc[i][3]));
      *(uint2*)&tSu[(n0 + i) * 72 + d0] = pk;
    }
    __syncthreads();
    // S_h[n,m] = sum_d' T[n,d'] * fwS[m,d'] ; tile 2n x 2m
    {
      const int m0 = te * 2;
      float sacc[2][2] = {};
      for (int kk = 0; kk < 8; kk++) {
        float ta0[8], ta1[8];
        unpack8(&tSu[n0 * 72 + kk * 8], ta0);
        unpack8(&tSu[(n0 + 1) * 72 + kk * 8], ta1);
        float f0[8], f1[8];
        *(float4*)&f0[0] = *(const float4*)&fwS[lidx(m0, kk * 8)];
        *(float4*)&f0[4] = *(const float4*)&fwS[lidx(m0, kk * 8 + 4)];
        *(float4*)&f1[0] = *(const float4*)&fwS[lidx(m0 + 1, kk * 8)];
        *(float4*)&f1[4] = *(const float4*)&fwS[lidx(m0 + 1, kk * 8 + 4)];
#pragma unroll
        for (int j = 0; j < 8; j++) {
          sacc[0][0] += ta0[j] * f0[j];
          sacc[0][1] += ta0[j] * f1[j];
          sacc[1][0] += ta1[j] * f0[j];
          sacc[1][1] += ta1[j] * f1[j];
        }
      }
      pS[(h * 32 + n0) * 33 + m0] = sacc[0][0];
      pS[(h * 32 + n0) * 33 + m0 + 1] = sacc[0][1];
      pS[(h * 32 + n0 + 1) * 33 + m0] = sacc[1][0];
      pS[(h * 32 + n0 + 1) * 33 + m0 + 1] = sacc[1][1];
    }
  }
  __syncthreads();

  // softmax over m per (h,n) row, in place
  if (t < 64) {
    const int base = t * 33;
    float mx = -1e30f;
    for (int m = 0; m < 32; m++) mx = fmaxf(mx, pS[base + m]);
    float sum = 0.f;
    for (int m = 0; m < 32; m++) { float e = __expf(pS[base + m] - mx); pS[base + m] = e; sum += e; }
    float inv = 1.0f / sum;
    for (int m = 0; m < 32; m++) pS[base + m] *= inv;
  }
  __syncthreads();

  // ---- vS = fwS . Wv (bf16 result), half-staged Wv ------------------------
  float acc[2][8] = {};
  for (int half = 0; half < 2; half++) {
#pragma unroll
    for (int k = 0; k < 4; k++) {
      int lin = t + 256 * k; int d = lin >> 5; int q = lin & 31;
      float4 v = *(const float4*)(Wv + (half * 32 + d) * 128 + q * 4);
      *(uint2*)&buf1u[d * 136 + q * 4] = make_uint2(pack2(v.x, v.y), pack2(v.z, v.w));
    }
    __syncthreads();
    for (int dq = 0; dq < 32; dq += 4) {
      float fw0[4], fw1[4];
      *(float4*)fw0 = *(const float4*)&fwS[lidx(n0, half * 32 + dq)];
      *(float4*)fw1 = *(const float4*)&fwS[lidx(n0 + 1, half * 32 + dq)];
#pragma unroll
      for (int j = 0; j < 4; j++) {
        float wrow[8];
        unpack8(&buf1u[(dq + j) * 136 + e0], wrow);
#pragma unroll
        for (int c = 0; c < 8; c++) {
          acc[0][c] += fw0[j] * wrow[c];
          acc[1][c] += fw1[j] * wrow[c];
        }
      }
    }
    __syncthreads();
  }
#pragma unroll
  for (int i = 0; i < 2; i++) {
    uint4 pk = make_uint4(pack2(acc[i][0], acc[i][1]), pack2(acc[i][2], acc[i][3]),
                          pack2(acc[i][4], acc[i][5]), pack2(acc[i][6], acc[i][7]));
    *(uint4*)&vSu[(n0 + i) * 136 + e0] = pk;
  }
  __syncthreads();

  // ---- out = P.v (+ fwS.Wr), relu, khi-weighted reduce --------------------
  const int h = te >> 3;
  float pacc[2][8] = {};
  for (int m = 0; m < 32; m++) {
    float p0 = pS[(h * 32 + n0) * 33 + m];
    float p1 = pS[(h * 32 + n0 + 1) * 33 + m];
    float vrow[8];
    unpack8(&vSu[m * 136 + e0], vrow);
#pragma unroll
    for (int j = 0; j < 8; j++) {
      pacc[0][j] += p0 * vrow[j];
      pacc[1][j] += p1 * vrow[j];
    }
  }
  for (int half = 0; half < 2; half++) {
#pragma unroll
    for (int k = 0; k < 4; k++) {
      int lin = t + 256 * k; int d = lin >> 5; int q = lin & 31;
      float4 v = *(const float4*)(Wr + (half * 32 + d) * 128 + q * 4);
      *(uint2*)&buf1u[d * 136 + q * 4] = make_uint2(pack2(v.x, v.y), pack2(v.z, v.w));
    }
    __syncthreads();
    for (int dq = 0; dq < 32; dq += 4) {
      float fw0[4], fw1[4];
      *(float4*)fw0 = *(const float4*)&fwS[lidx(n0, half * 32 + dq)];
      *(float4*)fw1 = *(const float4*)&fwS[lidx(n0 + 1, half * 32 + dq)];
#pragma unroll
      for (int j = 0; j < 4; j++) {
        float wrow[8];
        unpack8(&buf1u[(dq + j) * 136 + e0], wrow);
#pragma unroll
        for (int c = 0; c < 8; c++) {
          pacc[0][c] += fw0[j] * wrow[c];
          pacc[1][c] += fw1[j] * wrow[c];
        }
      }
    }
    __syncthreads();
  }
  {
    float kh0 = khi[n0], kh1 = khi[n0 + 1];
    float ph[8];
#pragma unroll
    for (int j = 0; j < 8; j++)
      ph[j] = kh0 * fmaxf(pacc[0][j], 0.f) + kh1 * fmaxf(pacc[1][j], 0.f);
    *(float4*)&redH[tn * 132 + e0] = *(float4*)&ph[0];
    *(float4*)&redH[tn * 132 + e0 + 4] = *(float4*)&ph[4];
  }
  // stage K (tS region dead since score phase)
  *(float4*)&Kf[t * 4] = *(const float4*)(Kb + t * 4);
  __syncthreads();

  // ---- high_int out + FM/MF partials --------------------------------------
  if (t < 128) {
    float s = 0.f;
#pragma unroll
    for (int k = 0; k < 16; k++) s += redH[k * 132 + t];
    out0[b * 256 + 128 + t] = s + bhi[t];
  }
  {
    const int c = t & 63, nq = t >> 6;
    float p = 0.f;
#pragma unroll
    for (int k = 0; k < 8; k++) {
      int nn = nq * 8 + k;
      float fv = fwS[lidx(nn, c)];
      float sv = ssq[b * 2048 + nn * 64 + c];
      p += (fv * fv - sv) * kfm[nn];
    }
    buf1f[nq * 68 + c] = p;
    // MF: 0.5 * fc^T K fc, quarter of l-rows per thread
    float fc[32];
#pragma unroll
    for (int r = 0; r < 32; r++) fc[r] = fwS[lidx(r, c)];
    float hmf = 0.f;
#pragma unroll
    for (int l8 = 0; l8 < 8; l8++) {
      int l = nq * 8 + l8;
      float inner = 0.f;
#pragma unroll
      for (int r = 0; r < 32; r++) inner += Kf[l * 32 + r] * fc[r];
      hmf += fc[l] * inner;
    }
    buf1f[(4 + nq) * 68 + c] = hmf;
  }
  __syncthreads();
  if (t < 64) {
    out0[b * 256 + t] = buf1f[t] + buf1f[68 + t] + buf1f[136 + t] + buf1f[204 + t] + bfm[t];
    float h2 = buf1f[272 + t] + buf1f[340 + t] + buf1f[408 + t] + buf1f[476 + t];
    out0[b * 256 + 64 + t] = 0.5f * h2 + bmf[t];
  }
}

// ---------------------------------------------------------------------------
extern "C" void kernel_launch(void* const* d_in, const int* in_sizes, int n_in,
                              void* d_out, int out_size, void* d_ws, size_t ws_size,
                              hipStream_t stream) {
  (void)in_sizes; (void)n_in; (void)out_size; (void)ws_size;
  const float* x     = (const float*)d_in[0];
  const float* W     = (const float*)d_in[1];
  const float* rinit = (const float*)d_in[2];
  const float* kfm   = (const float*)d_in[3];
  const float* bfm   = (const float*)d_in[4];
  const float* kmf   = (const float*)d_in[5];
  const float* bmf   = (const float*)d_in[6];
  const float* khi   = (const float*)d_in[7];
  const float* bhi   = (const float*)d_in[8];
  const float* Wq    = (const float*)d_in[9];
  const float* Wk    = (const float*)d_in[10];
  const float* Wv    = (const float*)d_in[11];
  const float* Wr    = (const float*)d_in[12];

  float* out0 = (float*)d_out;
  float* rs   = out0 + 1024 * 256;  // routing_score [B,32,64,1]

  float* ws   = (float*)d_ws;       // 24 MB
  float* xc   = ws;                 // [B,32,64]; A/K alias after k_fwv
  float* ow   = ws + 2097152;       // [B,32,64]; fwv aliases after k_upd(3)
  float* blog = ws + 2 * 2097152;   // [B,32,64]; ssq aliases after k_upd(3)
  float* fwv  = ow;
  float* ssq  = blog;
  float* Abuf = xc;                 // [2][64][64] = 8192 floats
  float* Kbuf = xc + 8192;          // [32][32]    = 1024 floats

  k_upd<<<1024, 256, 0, stream>>>(x, rinit, ow, blog, xc, rs, 0);
  for (int it = 1; it <= 3; it++) {
    k_sow<<<1024, 256, 0, stream>>>(W, xc, ow);
    k_upd<<<1024, 256, 0, stream>>>(x, rinit, ow, blog, xc, rs, it);
  }
  k_fwv<<<1024, 256, 0, stream>>>(W, xc, fwv);
  k_prep<<<9, 256, 0, stream>>>(Wq, Wk, kmf, Abuf, Kbuf);
  k_ih<<<4096, 256, 0, stream>>>(x, W, rs, ssq);
  k_attn<<<1024, 256, 0, stream>>>(fwv, ssq, Abuf, Kbuf, Wv, Wr,
                                   kfm, bfm, bmf, khi, bhi, out0);
}

// Round 4
// 292.971 us; speedup vs baseline: 3.4320x; 3.4320x over previous
//
#include <hip/hip_runtime.h>

// CapsuleLayer fused pipeline, round 4.
//  - R3's k_attn caused ~2 GB/dispatch of scratch (private-segment) HBM traffic:
//    helper fns taking array pointers + byte-blob LDS casts + launch_bounds(,4)
//    blocked register promotion. Rewritten in R2-k_int style: all-fp32, no
//    helpers-with-pointer-args, single __shared__ float pool, small unrolled
//    register arrays, Wv/Wr streamed from L2. LDS 34.5 KB -> 4 blocks/CU.
//  - Everything else unchanged from R3.

#define EPS_SQ 1e-7f

typedef __attribute__((ext_vector_type(8))) short bf16x8;
typedef __attribute__((ext_vector_type(4))) float floatx4;

__device__ __forceinline__ int lidx(int r, int c) {
  // 64-col fp32 tile, row stride 68 dwords, quad-swizzle
  return r * 68 + ((((c >> 2) ^ (r >> 2)) & 15) << 2) + (c & 3);
}
__device__ __forceinline__ unsigned short f2bf(float f) {
  unsigned u = __float_as_uint(f);
  u += 0x7FFFu + ((u >> 16) & 1u);   // RNE
  return (unsigned short)(u >> 16);
}

// ---------------------------------------------------------------------------
// k_upd(iter): [iter>0] blog += x . ow^T ; softmax over capsules (in place);
// xc = c . x ; [iter==3] write routing_score. One block per b.
// ---------------------------------------------------------------------------
__global__ __launch_bounds__(256) void k_upd(
    const float* __restrict__ x, const float* __restrict__ rinit,
    const float* __restrict__ ow, float* __restrict__ blog,
    float* __restrict__ xc, float* __restrict__ rs, int iter)
{
  __shared__ __align__(16) float xs[64 * 68];
  __shared__ __align__(16) float owS[32 * 68];
  __shared__ __align__(16) float bS[32 * 68];
  const int b = blockIdx.x, t = threadIdx.x;
  const float* xb = x + b * 4096;

#pragma unroll
  for (int k = 0; k < 4; k++) {
    int lin = t + 256 * k; int f = lin >> 4; int d0 = (lin & 15) << 2;
    *(float4*)&xs[lidx(f, d0)] = *(const float4*)(xb + f * 64 + d0);
  }
  {
    const float* src = (iter <= 1) ? rinit : (blog + b * 2048);
#pragma unroll
    for (int k = 0; k < 2; k++) {
      int lin = t + 256 * k; int n = lin >> 4; int f0 = (lin & 15) << 2;
      *(float4*)&bS[lidx(n, f0)] = *(const float4*)(src + n * 64 + f0);
    }
  }
  if (iter > 0) {
#pragma unroll
    for (int k = 0; k < 2; k++) {
      int lin = t + 256 * k; int n = lin >> 4; int d0 = (lin & 15) << 2;
      *(float4*)&owS[lidx(n, d0)] = *(const float4*)(ow + b * 2048 + n * 64 + d0);
    }
  }
  __syncthreads();

  const int tn = t >> 4, tlo = t & 15;

  if (iter > 0) {
    const int n0 = tn * 2, f0 = tlo * 4;
    float acc[2][4] = {{0, 0, 0, 0}, {0, 0, 0, 0}};
    for (int dq = 0; dq < 64; dq += 4) {
      float o[2][4];
      *(float4*)o[0] = *(const float4*)&owS[lidx(n0, dq)];
      *(float4*)o[1] = *(const float4*)&owS[lidx(n0 + 1, dq)];
#pragma unroll
      for (int i = 0; i < 4; i++) {
        float xr[4];
        *(float4*)xr = *(const float4*)&xs[lidx(f0 + i, dq)];
#pragma unroll
        for (int k = 0; k < 4; k++) {
          acc[0][i] += o[0][k] * xr[k];
          acc[1][i] += o[1][k] * xr[k];
        }
      }
    }
#pragma unroll
    for (int j = 0; j < 2; j++) {
      float tmp[4];
      *(float4*)tmp = *(const float4*)&bS[lidx(n0 + j, f0)];
#pragma unroll
      for (int i = 0; i < 4; i++) tmp[i] += acc[j][i];
      *(float4*)&bS[lidx(n0 + j, f0)] = *(float4*)tmp;
    }
    __syncthreads();
    if (iter < 3) {
#pragma unroll
      for (int k = 0; k < 2; k++) {
        int lin = t + 256 * k; int n = lin >> 4; int f0b = (lin & 15) << 2;
        *(float4*)(blog + b * 2048 + n * 64 + f0b) = *(const float4*)&bS[lidx(n, f0b)];
      }
    }
    __syncthreads();
  }

  // softmax over n per f column, in place in bS
  {
    const int n = t & 31, fg = t >> 5;
#pragma unroll
    for (int k = 0; k < 8; k++) {
      int f = fg * 8 + k;
      float v = bS[lidx(n, f)];
      float m = v;
      for (int s = 16; s > 0; s >>= 1) m = fmaxf(m, __shfl_xor(m, s, 64));
      float e = __expf(v - m);
      float sum = e;
      for (int s = 16; s > 0; s >>= 1) sum += __shfl_xor(sum, s, 64);
      bS[lidx(n, f)] = e / sum;
    }
  }
  __syncthreads();

  if (iter == 3) {
#pragma unroll
    for (int k = 0; k < 8; k++) {
      int lin = t + 256 * k; int n = lin >> 6, f = lin & 63;
      rs[b * 2048 + n * 64 + f] = bS[lidx(n, f)];
    }
  }
  // xc[n,d] = sum_f c[n,f]*x[f,d]
  {
    const int n0 = tn * 2, d0 = tlo * 4;
    float acc[2][4] = {{0, 0, 0, 0}, {0, 0, 0, 0}};
    for (int f = 0; f < 64; f++) {
      float c0v = bS[lidx(n0, f)];
      float c1v = bS[lidx(n0 + 1, f)];
      float xr[4];
      *(float4*)xr = *(const float4*)&xs[lidx(f, d0)];
#pragma unroll
      for (int i = 0; i < 4; i++) {
        acc[0][i] += c0v * xr[i];
        acc[1][i] += c1v * xr[i];
      }
    }
#pragma unroll
    for (int j = 0; j < 2; j++)
      *(float4*)(xc + b * 2048 + (n0 + j) * 64 + d0) = *(float4*)acc[j];
  }
}

// ---------------------------------------------------------------------------
// k_sow: per (n, 32-b chunk): s = xc.Mn ; o = squash(s) ; ow = Mn.o. grid 1024.
// ---------------------------------------------------------------------------
__global__ __launch_bounds__(256) void k_sow(
    const float* __restrict__ W, const float* __restrict__ xc,
    float* __restrict__ ow)
{
  __shared__ __align__(16) float Mn[64 * 68];
  __shared__ __align__(16) float xcS[32 * 68];
  __shared__ __align__(16) float sS[32 * 68];
  __shared__ float scaleS[32];
  const int n = blockIdx.x & 31, b0 = (blockIdx.x >> 5) * 32, t = threadIdx.x;

#pragma unroll
  for (int k = 0; k < 4; k++) {
    int lin = t + 256 * k; int d = lin >> 4; int c0 = (lin & 15) << 2;
    *(float4*)&Mn[lidx(d, c0)] = *(const float4*)(W + d * 2048 + n * 64 + c0);
  }
#pragma unroll
  for (int k = 0; k < 2; k++) {
    int lin = t + 256 * k; int bb = lin >> 4; int d0 = (lin & 15) << 2;
    *(float4*)&xcS[lidx(bb, d0)] = *(const float4*)(xc + (b0 + bb) * 2048 + n * 64 + d0);
  }
  __syncthreads();

  const int bb0 = (t >> 4) * 2, c4 = (t & 15) * 4;
  {
    float acc[2][4] = {};
    for (int dq = 0; dq < 64; dq += 4) {
      float xv0[4], xv1[4];
      *(float4*)xv0 = *(const float4*)&xcS[lidx(bb0, dq)];
      *(float4*)xv1 = *(const float4*)&xcS[lidx(bb0 + 1, dq)];
#pragma unroll
      for (int j = 0; j < 4; j++) {
        float mr[4];
        *(float4*)mr = *(const float4*)&Mn[lidx(dq + j, c4)];
#pragma unroll
        for (int c = 0; c < 4; c++) {
          acc[0][c] += xv0[j] * mr[c];
          acc[1][c] += xv1[j] * mr[c];
        }
      }
    }
    *(float4*)&sS[lidx(bb0, c4)] = *(float4*)acc[0];
    *(float4*)&sS[lidx(bb0 + 1, c4)] = *(float4*)acc[1];
  }
  __syncthreads();
  if (t < 32) {
    float ss = EPS_SQ;
    for (int c = 0; c < 64; c++) { float v = sS[lidx(t, c)]; ss += v * v; }
    scaleS[t] = sqrtf(ss) / (0.5f + ss);
  }
  __syncthreads();
  {
    float a2[2][4] = {};
    for (int cq = 0; cq < 64; cq += 4) {
      float sv0[4], sv1[4];
      *(float4*)sv0 = *(const float4*)&sS[lidx(bb0, cq)];
      *(float4*)sv1 = *(const float4*)&sS[lidx(bb0 + 1, cq)];
#pragma unroll
      for (int j = 0; j < 4; j++) {
        float mr[4];
        *(float4*)mr = *(const float4*)&Mn[lidx(c4 + j, cq)];
        float s0 = 0.f, s1 = 0.f;
#pragma unroll
        for (int k = 0; k < 4; k++) { s0 += sv0[k] * mr[k]; s1 += sv1[k] * mr[k]; }
        a2[0][j] += s0; a2[1][j] += s1;
      }
    }
#pragma unroll
    for (int i = 0; i < 2; i++) {
      float sc = scaleS[bb0 + i];
      float outv[4];
#pragma unroll
      for (int j = 0; j < 4; j++) outv[j] = a2[i][j] * sc;
      *(float4*)(ow + (b0 + bb0 + i) * 2048 + n * 64 + c4) = *(float4*)outv;
    }
  }
}

// ---------------------------------------------------------------------------
// k_fwv: fwv = xc_final . W (exact fp32), per (n, 32-b chunk). grid 1024.
// ---------------------------------------------------------------------------
__global__ __launch_bounds__(256) void k_fwv(
    const float* __restrict__ W, const float* __restrict__ xc,
    float* __restrict__ fwv)
{
  __shared__ __align__(16) float Mn[64 * 68];
  __shared__ __align__(16) float xcS[32 * 68];
  const int n = blockIdx.x & 31, b0 = (blockIdx.x >> 5) * 32, t = threadIdx.x;

#pragma unroll
  for (int k = 0; k < 4; k++) {
    int lin = t + 256 * k; int d = lin >> 4; int c0 = (lin & 15) << 2;
    *(float4*)&Mn[lidx(d, c0)] = *(const float4*)(W + d * 2048 + n * 64 + c0);
  }
#pragma unroll
  for (int k = 0; k < 2; k++) {
    int lin = t + 256 * k; int bb = lin >> 4; int d0 = (lin & 15) << 2;
    *(float4*)&xcS[lidx(bb, d0)] = *(const float4*)(xc + (b0 + bb) * 2048 + n * 64 + d0);
  }
  __syncthreads();

  const int bb0 = (t >> 4) * 2, c4 = (t & 15) * 4;
  float acc[2][4] = {};
  for (int dq = 0; dq < 64; dq += 4) {
    float xv0[4], xv1[4];
    *(float4*)xv0 = *(const float4*)&xcS[lidx(bb0, dq)];
    *(float4*)xv1 = *(const float4*)&xcS[lidx(bb0 + 1, dq)];
#pragma unroll
    for (int j = 0; j < 4; j++) {
      float mr[4];
      *(float4*)mr = *(const float4*)&Mn[lidx(dq + j, c4)];
#pragma unroll
      for (int c = 0; c < 4; c++) {
        acc[0][c] += xv0[j] * mr[c];
        acc[1][c] += xv1[j] * mr[c];
      }
    }
  }
  *(float4*)(fwv + (b0 + bb0) * 2048 + n * 64 + c4) = *(float4*)acc[0];
  *(float4*)(fwv + (b0 + bb0 + 1) * 2048 + n * 64 + c4) = *(float4*)acc[1];
}

// ---------------------------------------------------------------------------
// k_ih: ssq[b,n,c] = sum_f (c[n,f]*ih[b,n,f,c])^2 via bf16 MFMA (unchanged).
// ---------------------------------------------------------------------------
__global__ __launch_bounds__(256) void k_ih(
    const float* __restrict__ x, const float* __restrict__ W,
    const float* __restrict__ rs, float* __restrict__ ssq)
{
  __shared__ __align__(16) unsigned short xB[4 * 64 * 64];
  __shared__ __align__(16) unsigned short wB[2 * 64 * 64];
  __shared__ float cF2[4 * 2 * 64];
  const int n0 = (blockIdx.x & 15) * 2, g = blockIdx.x >> 4;
  const int b0 = g * 4;
  const int t = threadIdx.x, w = t >> 6, lane = t & 63;

#pragma unroll
  for (int k = 0; k < 16; k++) {
    int ch = t + 256 * k;
    int bb = ch >> 10, rem = ch & 1023;
    int f = rem >> 4, fq = rem & 15;
    int dg = fq >> 1, half = fq & 1;
    float4 v = *(const float4*)(x + ((b0 + bb) * 64 + f) * 64 + fq * 4);
    unsigned int p0 = f2bf(v.x) | ((unsigned)f2bf(v.y) << 16);
    unsigned int p1 = f2bf(v.z) | ((unsigned)f2bf(v.w) << 16);
    *(uint2*)&xB[bb * 4096 + f * 64 + ((dg ^ (f & 7)) << 3) + half * 4] =
        make_uint2(p0, p1);
  }
  {
    int dd = t >> 2, cq = t & 3;
    int dg = dd >> 3, dl = dd & 7;
#pragma unroll
    for (int nn = 0; nn < 2; nn++) {
      const float* wp = W + dd * 2048 + (n0 + nn) * 64 + cq * 16;
      unsigned short* base = wB + nn * 4096;
#pragma unroll
      for (int i4 = 0; i4 < 4; i4++) {
        float4 v = *(const float4*)(wp + i4 * 4);
        float vv[4] = {v.x, v.y, v.z, v.w};
#pragma unroll
        for (int j = 0; j < 4; j++) {
          int c = cq * 16 + i4 * 4 + j;
          base[c * 64 + ((dg ^ (c & 7)) << 3) + dl] = f2bf(vv[j]);
        }
      }
    }
  }
  {
#pragma unroll
    for (int nn = 0; nn < 2; nn++) {
      float v = rs[(b0 + w) * 2048 + (n0 + nn) * 64 + lane];
      cF2[(w * 2 + nn) * 64 + lane] = v * v;
    }
  }
  __syncthreads();

  const int m = lane & 15, q = lane >> 4, ms = m & 7;

  bf16x8 a[4][2];
#pragma unroll
  for (int mi = 0; mi < 4; mi++) {
    const unsigned short* bp = xB + w * 4096 + (mi * 16 + m) * 64;
#pragma unroll
    for (int kk = 0; kk < 2; kk++)
      a[mi][kk] = *(const bf16x8*)&bp[((kk * 4 + q) ^ ms) << 3];
  }

#pragma unroll
  for (int nn = 0; nn < 2; nn++) {
    bf16x8 bf[4][2];
#pragma unroll
    for (int ci = 0; ci < 4; ci++) {
      const unsigned short* bp = wB + nn * 4096 + (ci * 16 + m) * 64;
#pragma unroll
      for (int kk = 0; kk < 2; kk++)
        bf[ci][kk] = *(const bf16x8*)&bp[((kk * 4 + q) ^ ms) << 3];
    }
    float ps[4] = {0.f, 0.f, 0.f, 0.f};
    const float* cf = cF2 + (w * 2 + nn) * 64 + q * 4;
#pragma unroll
    for (int mi = 0; mi < 4; mi++) {
      float cfv[4];
#pragma unroll
      for (int r = 0; r < 4; r++) cfv[r] = cf[mi * 16 + r];
#pragma unroll
      for (int ci = 0; ci < 4; ci++) {
        floatx4 c0 = {0.f, 0.f, 0.f, 0.f};
        c0 = __builtin_amdgcn_mfma_f32_16x16x32_bf16(a[mi][0], bf[ci][0], c0, 0, 0, 0);
        c0 = __builtin_amdgcn_mfma_f32_16x16x32_bf16(a[mi][1], bf[ci][1], c0, 0, 0, 0);
#pragma unroll
        for (int r = 0; r < 4; r++) { float tv = c0[r]; ps[ci] += cfv[r] * tv * tv; }
      }
    }
#pragma unroll
    for (int ci = 0; ci < 4; ci++) {
      ps[ci] += __shfl_xor(ps[ci], 16, 64);
      ps[ci] += __shfl_xor(ps[ci], 32, 64);
    }
    if (q == 0) {
#pragma unroll
      for (int ci = 0; ci < 4; ci++)
        ssq[(b0 + w) * 2048 + (n0 + nn) * 64 + ci * 16 + m] = ps[ci];
    }
  }
}

// ---------------------------------------------------------------------------
// k_prep: blocks 0..7: A_h = Wq_h . Wk_h^T. block 8: pair matrix K from kmf.
// ---------------------------------------------------------------------------
__global__ __launch_bounds__(256) void k_prep(
    const float* __restrict__ Wq, const float* __restrict__ Wk,
    const float* __restrict__ kmf, float* __restrict__ Ab, float* __restrict__ Kb)
{
  const int t = threadIdx.x;
  if (blockIdx.x < 8) {
    __shared__ __align__(16) float wkS[64 * 68];
    __shared__ __align__(16) float wqS[16 * 68];
    const int h = blockIdx.x & 1, rg = blockIdx.x >> 1;
#pragma unroll
    for (int k = 0; k < 4; k++) {
      int lin = t + 256 * k; int dp = lin >> 4; int e0 = (lin & 15) << 2;
      *(float4*)&wkS[lidx(dp, e0)] = *(const float4*)(Wk + dp * 128 + h * 64 + e0);
    }
    {
      int dl = t >> 4, e0 = (t & 15) << 2;
      *(float4*)&wqS[lidx(dl, e0)] = *(const float4*)(Wq + (rg * 16 + dl) * 128 + h * 64 + e0);
    }
    __syncthreads();
    const int dl = t >> 4, dp0 = (t & 15) << 2;
    float acc[4] = {};
    for (int e = 0; e < 64; e += 4) {
      float q4[4];
      *(float4*)q4 = *(const float4*)&wqS[lidx(dl, e)];
#pragma unroll
      for (int c = 0; c < 4; c++) {
        float mr[4];
        *(float4*)mr = *(const float4*)&wkS[lidx(dp0 + c, e)];
        acc[c] += q4[0] * mr[0] + q4[1] * mr[1] + q4[2] * mr[2] + q4[3] * mr[3];
      }
    }
    *(float4*)(Ab + h * 4096 + (rg * 16 + dl) * 64 + dp0) = *(float4*)acc;
  } else {
    __shared__ float Ks[1024];
    *(float4*)&Ks[t * 4] = make_float4(0.f, 0.f, 0.f, 0.f);
    __syncthreads();
    if (t < 248) {
#pragma unroll
      for (int j = 0; j < 2; j++) {
        int p = t * 2 + j;
        if (p < 496) {
          int l = 0, rem = p;
          while (rem >= 31 - l) { rem -= 31 - l; ++l; }
          int r = l + 1 + rem;
          float v = kmf[p];
          Ks[l * 32 + r] = v;
          Ks[r * 32 + l] = v;
        }
      }
    }
    __syncthreads();
    *(float4*)&Kb[t * 4] = *(const float4*)&Ks[t * 4];
  }
}

// ---------------------------------------------------------------------------
// k_attn: per-b fused attention + FM + MF + high_int. One block per b.
// fp32 only, 34.5 KB LDS -> 4 blocks/CU. Wv/Wr streamed from L2.
// ---------------------------------------------------------------------------
__global__ __launch_bounds__(256) void k_attn(
    const float* __restrict__ fwv, const float* __restrict__ ssq,
    const float* __restrict__ Ab, const float* __restrict__ Kb,
    const float* __restrict__ Wv, const float* __restrict__ Wr,
    const float* __restrict__ kfm, const float* __restrict__ bfm,
    const float* __restrict__ bmf, const float* __restrict__ khi,
    const float* __restrict__ bhi, float* __restrict__ out0)
{
  __shared__ __align__(16) float smem[8640];   // 34560 B
  float* fwS  = smem;               // 32x68 (2176 f)
  float* pS   = smem + 2176;        // 64x33 (2112 f) scores/probs; redH alias
  float* bufA = smem + 4288;        // 32x68 (2176 f) A-half; vS spans bufA+tS
  float* tS   = smem + 6464;        // 32x68 (2176 f) T
  float* vS   = smem + 4288;        // 32x132 (4224 f) value matrix (alias)
  float* redH = smem + 2176;        // 16x132 (2112 f) (alias of pS)
  float* Kf   = smem + 4288;        // 32x32 (1024 f) (alias, post-vS)
  float* red1 = smem + 5312;        // 8x68 (544 f)

  const int b = blockIdx.x, t = threadIdx.x;
  const int tn = t >> 4, te = t & 15;
  const int n0 = tn * 2, e0 = te * 8, d0 = te * 4;

#pragma unroll
  for (int k = 0; k < 2; k++) {
    int lin = t + 256 * k; int nn = lin >> 4; int c0 = (lin & 15) << 2;
    *(float4*)&fwS[lidx(nn, c0)] = *(const float4*)(fwv + b * 2048 + nn * 64 + c0);
  }
  __syncthreads();

  // ---- scores: S_h = (fwS . A_h) . fwS^T ----------------------------------
  for (int h = 0; h < 2; h++) {
    float tacc[2][4] = {};
    for (int half = 0; half < 2; half++) {
#pragma unroll
      for (int k = 0; k < 2; k++) {
        int lin = t + 256 * k; int d = lin >> 4; int c0 = (lin & 15) << 2;
        *(float4*)&bufA[lidx(d, c0)] =
            *(const float4*)(Ab + h * 4096 + (half * 32 + d) * 64 + c0);
      }
      __syncthreads();
      for (int dq = 0; dq < 32; dq += 4) {
        float fw0[4], fw1[4];
        *(float4*)fw0 = *(const float4*)&fwS[lidx(n0, half * 32 + dq)];
        *(float4*)fw1 = *(const float4*)&fwS[lidx(n0 + 1, half * 32 + dq)];
#pragma unroll
        for (int j = 0; j < 4; j++) {
          float mr[4];
          *(float4*)mr = *(const float4*)&bufA[lidx(dq + j, d0)];
#pragma unroll
          for (int c = 0; c < 4; c++) {
            tacc[0][c] += fw0[j] * mr[c];
            tacc[1][c] += fw1[j] * mr[c];
          }
        }
      }
      __syncthreads();
    }
    *(float4*)&tS[lidx(n0, d0)] = *(float4*)tacc[0];
    *(float4*)&tS[lidx(n0 + 1, d0)] = *(float4*)tacc[1];
    __syncthreads();
    {
      const int m0 = te * 2;
      float s00 = 0.f, s01 = 0.f, s10 = 0.f, s11 = 0.f;
      for (int kk = 0; kk < 16; kk++) {
        float ta0[4], ta1[4], f0[4], f1[4];
        *(float4*)ta0 = *(const float4*)&tS[lidx(n0, kk * 4)];
        *(float4*)ta1 = *(const float4*)&tS[lidx(n0 + 1, kk * 4)];
        *(float4*)f0 = *(const float4*)&fwS[lidx(m0, kk * 4)];
        *(float4*)f1 = *(const float4*)&fwS[lidx(m0 + 1, kk * 4)];
#pragma unroll
        for (int j = 0; j < 4; j++) {
          s00 += ta0[j] * f0[j]; s01 += ta0[j] * f1[j];
          s10 += ta1[j] * f0[j]; s11 += ta1[j] * f1[j];
        }
      }
      pS[(h * 32 + n0) * 33 + m0] = s00;
      pS[(h * 32 + n0) * 33 + m0 + 1] = s01;
      pS[(h * 32 + n0 + 1) * 33 + m0] = s10;
      pS[(h * 32 + n0 + 1) * 33 + m0 + 1] = s11;
    }
    __syncthreads();
  }

  // ---- softmax over m per (h,n) row, in place -----------------------------
  if (t < 64) {
    const int base = t * 33;
    float mx = -1e30f;
    for (int m = 0; m < 32; m++) mx = fmaxf(mx, pS[base + m]);
    float sum = 0.f;
    for (int m = 0; m < 32; m++) { float e = __expf(pS[base + m] - mx); pS[base + m] = e; sum += e; }
    float inv = 1.0f / sum;
    for (int m = 0; m < 32; m++) pS[base + m] *= inv;
  }
  __syncthreads();

  // ---- vS = fwS . Wv (Wv streamed from L2) --------------------------------
  {
    float acc[2][8] = {};
    for (int dq = 0; dq < 64; dq += 4) {
      float fw0[4], fw1[4];
      *(float4*)fw0 = *(const float4*)&fwS[lidx(n0, dq)];
      *(float4*)fw1 = *(const float4*)&fwS[lidx(n0 + 1, dq)];
#pragma unroll
      for (int jj = 0; jj < 4; jj++) {
        float w8[8];
        *(float4*)&w8[0] = *(const float4*)(Wv + (dq + jj) * 128 + e0);
        *(float4*)&w8[4] = *(const float4*)(Wv + (dq + jj) * 128 + e0 + 4);
#pragma unroll
        for (int j = 0; j < 8; j++) {
          acc[0][j] += fw0[jj] * w8[j];
          acc[1][j] += fw1[jj] * w8[j];
        }
      }
    }
    *(float4*)&vS[n0 * 132 + e0] = *(float4*)&acc[0][0];
    *(float4*)&vS[n0 * 132 + e0 + 4] = *(float4*)&acc[0][4];
    *(float4*)&vS[(n0 + 1) * 132 + e0] = *(float4*)&acc[1][0];
    *(float4*)&vS[(n0 + 1) * 132 + e0 + 4] = *(float4*)&acc[1][4];
  }
  __syncthreads();

  // ---- out = P.v + fwS.Wr, relu, khi-weighted reduce ----------------------
  {
    const int h2 = te >> 3;
    float pacc[2][8] = {};
    for (int m = 0; m < 32; m++) {
      float p0 = pS[(h2 * 32 + n0) * 33 + m];
      float p1 = pS[(h2 * 32 + n0 + 1) * 33 + m];
      float vr[8];
      *(float4*)&vr[0] = *(const float4*)&vS[m * 132 + e0];
      *(float4*)&vr[4] = *(const float4*)&vS[m * 132 + e0 + 4];
#pragma unroll
      for (int j = 0; j < 8; j++) {
        pacc[0][j] += p0 * vr[j];
        pacc[1][j] += p1 * vr[j];
      }
    }
    for (int dq = 0; dq < 64; dq += 4) {
      float fw0[4], fw1[4];
      *(float4*)fw0 = *(const float4*)&fwS[lidx(n0, dq)];
      *(float4*)fw1 = *(const float4*)&fwS[lidx(n0 + 1, dq)];
#pragma unroll
      for (int jj = 0; jj < 4; jj++) {
        float w8[8];
        *(float4*)&w8[0] = *(const float4*)(Wr + (dq + jj) * 128 + e0);
        *(float4*)&w8[4] = *(const float4*)(Wr + (dq + jj) * 128 + e0 + 4);
#pragma unroll
        for (int j = 0; j < 8; j++) {
          pacc[0][j] += fw0[jj] * w8[j];
          pacc[1][j] += fw1[jj] * w8[j];
        }
      }
    }
    __syncthreads();   // all pS/vS readers done; redH (pS) & Kf (vS) writes follow
    {
      float kh0 = khi[n0], kh1 = khi[n0 + 1];
      float ph[8];
#pragma unroll
      for (int j = 0; j < 8; j++)
        ph[j] = kh0 * fmaxf(pacc[0][j], 0.f) + kh1 * fmaxf(pacc[1][j], 0.f);
      *(float4*)&redH[tn * 132 + e0] = *(float4*)&ph[0];
      *(float4*)&redH[tn * 132 + e0 + 4] = *(float4*)&ph[4];
    }
  }
  *(float4*)&Kf[t * 4] = *(const float4*)(Kb + t * 4);
  __syncthreads();

  // ---- high_int out + FM/MF partials --------------------------------------
  if (t < 128) {
    float s = 0.f;
#pragma unroll
    for (int k = 0; k < 16; k++) s += redH[k * 132 + t];
    out0[b * 256 + 128 + t] = s + bhi[t];
  }
  {
    const int c = t & 63, nq = t >> 6;
    float p = 0.f;
#pragma unroll
    for (int k = 0; k < 8; k++) {
      int nn = nq * 8 + k;
      float fv = fwS[lidx(nn, c)];
      float sv = ssq[b * 2048 + nn * 64 + c];
      p += (fv * fv - sv) * kfm[nn];
    }
    red1[nq * 68 + c] = p;
    // MF: 0.5 * fw^T K fw column c; loop-inverted, K reads wave-uniform
    float inner[8] = {};
    for (int r = 0; r < 32; r++) {
      float fr = fwS[lidx(r, c)];
#pragma unroll
      for (int l8 = 0; l8 < 8; l8++)
        inner[l8] += Kf[(nq * 8 + l8) * 32 + r] * fr;
    }
    float hmf = 0.f;
#pragma unroll
    for (int l8 = 0; l8 < 8; l8++)
      hmf += fwS[lidx(nq * 8 + l8, c)] * inner[l8];
    red1[(4 + nq) * 68 + c] = hmf;
  }
  __syncthreads();
  if (t < 64) {
    out0[b * 256 + t] = red1[t] + red1[68 + t] + red1[136 + t] + red1[204 + t] + bfm[t];
    float h2 = red1[272 + t] + red1[340 + t] + red1[408 + t] + red1[476 + t];
    out0[b * 256 + 64 + t] = 0.5f * h2 + bmf[t];
  }
}

// ---------------------------------------------------------------------------
extern "C" void kernel_launch(void* const* d_in, const int* in_sizes, int n_in,
                              void* d_out, int out_size, void* d_ws, size_t ws_size,
                              hipStream_t stream) {
  (void)in_sizes; (void)n_in; (void)out_size; (void)ws_size;
  const float* x     = (const float*)d_in[0];
  const float* W     = (const float*)d_in[1];
  const float* rinit = (const float*)d_in[2];
  const float* kfm   = (const float*)d_in[3];
  const float* bfm   = (const float*)d_in[4];
  const float* kmf   = (const float*)d_in[5];
  const float* bmf   = (const float*)d_in[6];
  const float* khi   = (const float*)d_in[7];
  const float* bhi   = (const float*)d_in[8];
  const float* Wq    = (const float*)d_in[9];
  const float* Wk    = (const float*)d_in[10];
  const float* Wv    = (const float*)d_in[11];
  const float* Wr    = (const float*)d_in[12];

  float* out0 = (float*)d_out;
  float* rs   = out0 + 1024 * 256;  // routing_score [B,32,64,1]

  float* ws   = (float*)d_ws;       // 24 MB
  float* xc   = ws;                 // [B,32,64]; A/K alias after k_fwv
  float* ow   = ws + 2097152;       // [B,32,64]; fwv aliases after k_upd(3)
  float* blog = ws + 2 * 2097152;   // [B,32,64]; ssq aliases after k_upd(3)
  float* fwv  = ow;
  float* ssq  = blog;
  float* Abuf = xc;                 // [2][64][64] = 8192 floats
  float* Kbuf = xc + 8192;          // [32][32]    = 1024 floats

  k_upd<<<1024, 256, 0, stream>>>(x, rinit, ow, blog, xc, rs, 0);
  for (int it = 1; it <= 3; it++) {
    k_sow<<<1024, 256, 0, stream>>>(W, xc, ow);
    k_upd<<<1024, 256, 0, stream>>>(x, rinit, ow, blog, xc, rs, it);
  }
  k_fwv<<<1024, 256, 0, stream>>>(W, xc, fwv);
  k_prep<<<9, 256, 0, stream>>>(Wq, Wk, kmf, Abuf, Kbuf);
  k_ih<<<4096, 256, 0, stream>>>(x, W, rs, ssq);
  k_attn<<<1024, 256, 0, stream>>>(fwv, ssq, Abuf, Kbuf, Wv, Wr,
                                   kfm, bfm, bmf, khi, bhi, out0);
}

// Round 5
// 280.460 us; speedup vs baseline: 3.5850x; 1.0446x over previous
//
#include <hip/hip_runtime.h>

// CapsuleLayer fused pipeline, round 5.
//  - Q-trick (exact): ow = scale * xc.Q_n, |s|^2 = xc.Q_n.xc^T with
//    Q_n = M_n.M_n^T precomputed by k_prepq into the rs output region
//    (free until k_upd(3) writes routing_score). k_sowq replaces k_sow:
//    half the GEMM FLOPs, one sync, no sS round-trip.
//  - k_ih v2: block = (4 b's) x (8 n's), loops 4 n-pairs staging wB per pair;
//    x staged ONCE -> x traffic 256 MB -> 64 MB. cF2 in bf16 (53.2 KB LDS,
//    3 blocks/CU).
//  - k_attn: softmax parallelized 4 threads/row (pS stride 36, aligned float4).
//  - Style rules from R3 post-mortem: no helpers taking array pointers, typed
//    __shared__ arrays, small fully-unrolled register arrays.

#define EPS_SQ 1e-7f

typedef __attribute__((ext_vector_type(8))) short bf16x8;
typedef __attribute__((ext_vector_type(4))) float floatx4;

__device__ __forceinline__ int lidx(int r, int c) {
  // 64-col fp32 tile, row stride 68 dwords, quad-swizzle
  return r * 68 + ((((c >> 2) ^ (r >> 2)) & 15) << 2) + (c & 3);
}
__device__ __forceinline__ unsigned short f2bf(float f) {
  unsigned u = __float_as_uint(f);
  u += 0x7FFFu + ((u >> 16) & 1u);   // RNE
  return (unsigned short)(u >> 16);
}

// ---------------------------------------------------------------------------
// k_upd(iter): [iter>0] blog += x . ow^T ; softmax over capsules (in place);
// xc = c . x ; [iter==3] write routing_score. One block per b. (unchanged R4)
// ---------------------------------------------------------------------------
__global__ __launch_bounds__(256) void k_upd(
    const float* __restrict__ x, const float* __restrict__ rinit,
    const float* __restrict__ ow, float* __restrict__ blog,
    float* __restrict__ xc, float* __restrict__ rs, int iter)
{
  __shared__ __align__(16) float xs[64 * 68];
  __shared__ __align__(16) float owS[32 * 68];
  __shared__ __align__(16) float bS[32 * 68];
  const int b = blockIdx.x, t = threadIdx.x;
  const float* xb = x + b * 4096;

#pragma unroll
  for (int k = 0; k < 4; k++) {
    int lin = t + 256 * k; int f = lin >> 4; int d0 = (lin & 15) << 2;
    *(float4*)&xs[lidx(f, d0)] = *(const float4*)(xb + f * 64 + d0);
  }
  {
    const float* src = (iter <= 1) ? rinit : (blog + b * 2048);
#pragma unroll
    for (int k = 0; k < 2; k++) {
      int lin = t + 256 * k; int n = lin >> 4; int f0 = (lin & 15) << 2;
      *(float4*)&bS[lidx(n, f0)] = *(const float4*)(src + n * 64 + f0);
    }
  }
  if (iter > 0) {
#pragma unroll
    for (int k = 0; k < 2; k++) {
      int lin = t + 256 * k; int n = lin >> 4; int d0 = (lin & 15) << 2;
      *(float4*)&owS[lidx(n, d0)] = *(const float4*)(ow + b * 2048 + n * 64 + d0);
    }
  }
  __syncthreads();

  const int tn = t >> 4, tlo = t & 15;

  if (iter > 0) {
    const int n0 = tn * 2, f0 = tlo * 4;
    float acc[2][4] = {{0, 0, 0, 0}, {0, 0, 0, 0}};
    for (int dq = 0; dq < 64; dq += 4) {
      float o[2][4];
      *(float4*)o[0] = *(const float4*)&owS[lidx(n0, dq)];
      *(float4*)o[1] = *(const float4*)&owS[lidx(n0 + 1, dq)];
#pragma unroll
      for (int i = 0; i < 4; i++) {
        float xr[4];
        *(float4*)xr = *(const float4*)&xs[lidx(f0 + i, dq)];
#pragma unroll
        for (int k = 0; k < 4; k++) {
          acc[0][i] += o[0][k] * xr[k];
          acc[1][i] += o[1][k] * xr[k];
        }
      }
    }
#pragma unroll
    for (int j = 0; j < 2; j++) {
      float tmp[4];
      *(float4*)tmp = *(const float4*)&bS[lidx(n0 + j, f0)];
#pragma unroll
      for (int i = 0; i < 4; i++) tmp[i] += acc[j][i];
      *(float4*)&bS[lidx(n0 + j, f0)] = *(float4*)tmp;
    }
    __syncthreads();
    if (iter < 3) {
#pragma unroll
      for (int k = 0; k < 2; k++) {
        int lin = t + 256 * k; int n = lin >> 4; int f0b = (lin & 15) << 2;
        *(float4*)(blog + b * 2048 + n * 64 + f0b) = *(const float4*)&bS[lidx(n, f0b)];
      }
    }
    __syncthreads();
  }

  // softmax over n per f column, in place in bS
  {
    const int n = t & 31, fg = t >> 5;
#pragma unroll
    for (int k = 0; k < 8; k++) {
      int f = fg * 8 + k;
      float v = bS[lidx(n, f)];
      float m = v;
      for (int s = 16; s > 0; s >>= 1) m = fmaxf(m, __shfl_xor(m, s, 64));
      float e = __expf(v - m);
      float sum = e;
      for (int s = 16; s > 0; s >>= 1) sum += __shfl_xor(sum, s, 64);
      bS[lidx(n, f)] = e / sum;
    }
  }
  __syncthreads();

  if (iter == 3) {
#pragma unroll
    for (int k = 0; k < 8; k++) {
      int lin = t + 256 * k; int n = lin >> 6, f = lin & 63;
      rs[b * 2048 + n * 64 + f] = bS[lidx(n, f)];
    }
  }
  // xc[n,d] = sum_f c[n,f]*x[f,d]
  {
    const int n0 = tn * 2, d0 = tlo * 4;
    float acc[2][4] = {{0, 0, 0, 0}, {0, 0, 0, 0}};
    for (int f = 0; f < 64; f++) {
      float c0v = bS[lidx(n0, f)];
      float c1v = bS[lidx(n0 + 1, f)];
      float xr[4];
      *(float4*)xr = *(const float4*)&xs[lidx(f, d0)];
#pragma unroll
      for (int i = 0; i < 4; i++) {
        acc[0][i] += c0v * xr[i];
        acc[1][i] += c1v * xr[i];
      }
    }
#pragma unroll
    for (int j = 0; j < 2; j++)
      *(float4*)(xc + b * 2048 + (n0 + j) * 64 + d0) = *(float4*)acc[j];
  }
}

// ---------------------------------------------------------------------------
// k_prepq: Q_n = M_n . M_n^T, one block per n (grid 32). Output to rs region.
// ---------------------------------------------------------------------------
__global__ __launch_bounds__(256) void k_prepq(
    const float* __restrict__ W, float* __restrict__ Qb)
{
  __shared__ __align__(16) float Mn[64 * 68];
  const int n = blockIdx.x, t = threadIdx.x;
#pragma unroll
  for (int k = 0; k < 4; k++) {
    int lin = t + 256 * k; int d = lin >> 4; int c0 = (lin & 15) << 2;
    *(float4*)&Mn[lidx(d, c0)] = *(const float4*)(W + d * 2048 + n * 64 + c0);
  }
  __syncthreads();
  const int d1 = (t >> 4) * 4, d2 = (t & 15) * 4;
  float acc[4][4] = {};
  for (int cq = 0; cq < 64; cq += 4) {
    float m1[4][4], m2[4][4];
#pragma unroll
    for (int i = 0; i < 4; i++) *(float4*)m1[i] = *(const float4*)&Mn[lidx(d1 + i, cq)];
#pragma unroll
    for (int j = 0; j < 4; j++) *(float4*)m2[j] = *(const float4*)&Mn[lidx(d2 + j, cq)];
#pragma unroll
    for (int i = 0; i < 4; i++)
#pragma unroll
      for (int j = 0; j < 4; j++) {
        float s = 0.f;
#pragma unroll
        for (int k = 0; k < 4; k++) s += m1[i][k] * m2[j][k];
        acc[i][j] += s;
      }
  }
#pragma unroll
  for (int i = 0; i < 4; i++)
    *(float4*)(Qb + n * 4096 + (d1 + i) * 64 + d2) = *(float4*)acc[i];
}

// ---------------------------------------------------------------------------
// k_sowq: per (n, 32-b chunk): y = xc.Q_n ; ss = y.xc ; ow = scale*y.
// Replaces k_sow via Q-trick (exact). One sync. grid 1024.
// ---------------------------------------------------------------------------
__global__ __launch_bounds__(256) void k_sowq(
    const float* __restrict__ Qb, const float* __restrict__ xc,
    float* __restrict__ ow)
{
  __shared__ __align__(16) float Qs[64 * 68];
  __shared__ __align__(16) float xcS[32 * 68];
  const int n = blockIdx.x & 31, b0 = (blockIdx.x >> 5) * 32, t = threadIdx.x;

#pragma unroll
  for (int k = 0; k < 4; k++) {
    int lin = t + 256 * k; int d1 = lin >> 4; int d2 = (lin & 15) << 2;
    *(float4*)&Qs[lidx(d1, d2)] = *(const float4*)(Qb + n * 4096 + d1 * 64 + d2);
  }
#pragma unroll
  for (int k = 0; k < 2; k++) {
    int lin = t + 256 * k; int bb = lin >> 4; int d0 = (lin & 15) << 2;
    *(float4*)&xcS[lidx(bb, d0)] = *(const float4*)(xc + (b0 + bb) * 2048 + n * 64 + d0);
  }
  __syncthreads();

  const int bb0 = (t >> 4) * 2, d4 = (t & 15) * 4;
  float y0[4] = {}, y1[4] = {};
  for (int dq = 0; dq < 64; dq += 4) {
    float x0[4], x1[4];
    *(float4*)x0 = *(const float4*)&xcS[lidx(bb0, dq)];
    *(float4*)x1 = *(const float4*)&xcS[lidx(bb0 + 1, dq)];
#pragma unroll
    for (int j = 0; j < 4; j++) {
      float qr[4];
      *(float4*)qr = *(const float4*)&Qs[lidx(dq + j, d4)];
#pragma unroll
      for (int c = 0; c < 4; c++) {
        y0[c] += x0[j] * qr[c];
        y1[c] += x1[j] * qr[c];
      }
    }
  }
  // ss = y . xc, reduced across the 16 threads (te) sharing a b-pair
  float xa[4], xb2[4];
  *(float4*)xa = *(const float4*)&xcS[lidx(bb0, d4)];
  *(float4*)xb2 = *(const float4*)&xcS[lidx(bb0 + 1, d4)];
  float s0 = 0.f, s1 = 0.f;
#pragma unroll
  for (int c = 0; c < 4; c++) { s0 += y0[c] * xa[c]; s1 += y1[c] * xb2[c]; }
#pragma unroll
  for (int sh = 1; sh <= 8; sh <<= 1) {
    s0 += __shfl_xor(s0, sh, 64);
    s1 += __shfl_xor(s1, sh, 64);
  }
  s0 += EPS_SQ; s1 += EPS_SQ;
  const float sc0 = sqrtf(s0) / (0.5f + s0);
  const float sc1 = sqrtf(s1) / (0.5f + s1);
  float o0[4], o1[4];
#pragma unroll
  for (int c = 0; c < 4; c++) { o0[c] = y0[c] * sc0; o1[c] = y1[c] * sc1; }
  *(float4*)(ow + (b0 + bb0) * 2048 + n * 64 + d4) = *(float4*)o0;
  *(float4*)(ow + (b0 + bb0 + 1) * 2048 + n * 64 + d4) = *(float4*)o1;
}

// ---------------------------------------------------------------------------
// k_fwv: fwv = xc_final . W (exact fp32), per (n, 32-b chunk). grid 1024.
// ---------------------------------------------------------------------------
__global__ __launch_bounds__(256) void k_fwv(
    const float* __restrict__ W, const float* __restrict__ xc,
    float* __restrict__ fwv)
{
  __shared__ __align__(16) float Mn[64 * 68];
  __shared__ __align__(16) float xcS[32 * 68];
  const int n = blockIdx.x & 31, b0 = (blockIdx.x >> 5) * 32, t = threadIdx.x;

#pragma unroll
  for (int k = 0; k < 4; k++) {
    int lin = t + 256 * k; int d = lin >> 4; int c0 = (lin & 15) << 2;
    *(float4*)&Mn[lidx(d, c0)] = *(const float4*)(W + d * 2048 + n * 64 + c0);
  }
#pragma unroll
  for (int k = 0; k < 2; k++) {
    int lin = t + 256 * k; int bb = lin >> 4; int d0 = (lin & 15) << 2;
    *(float4*)&xcS[lidx(bb, d0)] = *(const float4*)(xc + (b0 + bb) * 2048 + n * 64 + d0);
  }
  __syncthreads();

  const int bb0 = (t >> 4) * 2, c4 = (t & 15) * 4;
  float acc[2][4] = {};
  for (int dq = 0; dq < 64; dq += 4) {
    float xv0[4], xv1[4];
    *(float4*)xv0 = *(const float4*)&xcS[lidx(bb0, dq)];
    *(float4*)xv1 = *(const float4*)&xcS[lidx(bb0 + 1, dq)];
#pragma unroll
    for (int j = 0; j < 4; j++) {
      float mr[4];
      *(float4*)mr = *(const float4*)&Mn[lidx(dq + j, c4)];
#pragma unroll
      for (int c = 0; c < 4; c++) {
        acc[0][c] += xv0[j] * mr[c];
        acc[1][c] += xv1[j] * mr[c];
      }
    }
  }
  *(float4*)(fwv + (b0 + bb0) * 2048 + n * 64 + c4) = *(float4*)acc[0];
  *(float4*)(fwv + (b0 + bb0 + 1) * 2048 + n * 64 + c4) = *(float4*)acc[1];
}

// ---------------------------------------------------------------------------
// k_ih v2: ssq via bf16 MFMA. Block = 4 b's x 8 n's (loop 4 n-pairs), grid 1024.
// x staged ONCE per block (was 4x re-read across n-pair blocks). cF2 bf16.
// LDS 53.2 KB -> 3 blocks/CU.
// ---------------------------------------------------------------------------
__global__ __launch_bounds__(256) void k_ih(
    const float* __restrict__ x, const float* __restrict__ W,
    const float* __restrict__ rs, float* __restrict__ ssq)
{
  __shared__ __align__(16) unsigned short xB[4 * 64 * 64];   // 32768 B
  __shared__ __align__(16) unsigned short wB[2 * 64 * 64];   // 16384 B
  __shared__ unsigned short cF2[4 * 8 * 64];                 // 4096 B (bf16 c^2)
  const int n_oct = (blockIdx.x & 3) << 3, b0 = (blockIdx.x >> 2) * 4;
  const int t = threadIdx.x, w = t >> 6, lane = t & 63;

  // stage x -> bf16 (once)
#pragma unroll
  for (int k = 0; k < 16; k++) {
    int ch = t + 256 * k;
    int bb = ch >> 10, rem = ch & 1023;
    int f = rem >> 4, fq = rem & 15;
    int dg = fq >> 1, half = fq & 1;
    float4 v = *(const float4*)(x + ((b0 + bb) * 64 + f) * 64 + fq * 4);
    unsigned p0 = f2bf(v.x) | ((unsigned)f2bf(v.y) << 16);
    unsigned p1 = f2bf(v.z) | ((unsigned)f2bf(v.w) << 16);
    *(uint2*)&xB[bb * 4096 + f * 64 + ((dg ^ (f & 7)) << 3) + half * 4] =
        make_uint2(p0, p1);
  }
  // stage c^2 (bf16) for 8 n's
#pragma unroll
  for (int nn = 0; nn < 8; nn++) {
    float v = rs[(b0 + w) * 2048 + (n_oct + nn) * 64 + lane];
    cF2[(w * 8 + nn) * 64 + lane] = f2bf(v * v);
  }
  __syncthreads();

  const int m = lane & 15, q = lane >> 4, ms = m & 7;
  bf16x8 a[4][2];
#pragma unroll
  for (int mi = 0; mi < 4; mi++) {
    const unsigned short* bp = xB + w * 4096 + (mi * 16 + m) * 64;
#pragma unroll
    for (int kk = 0; kk < 2; kk++)
      a[mi][kk] = *(const bf16x8*)&bp[((kk * 4 + q) ^ ms) << 3];
  }

  for (int np = 0; np < 4; np++) {
    const int n0 = n_oct + np * 2;
    __syncthreads();                 // prior-iteration wB readers done
    { // stage W (bf16, transposed) for n0, n0+1
      int dd = t >> 2, cq = t & 3;
      int dg = dd >> 3, dl = dd & 7;
#pragma unroll
      for (int nn = 0; nn < 2; nn++) {
        const float* wp = W + dd * 2048 + (n0 + nn) * 64 + cq * 16;
        unsigned short* base = wB + nn * 4096;
#pragma unroll
        for (int i4 = 0; i4 < 4; i4++) {
          float4 v = *(const float4*)(wp + i4 * 4);
          float vv[4] = {v.x, v.y, v.z, v.w};
#pragma unroll
          for (int j = 0; j < 4; j++) {
            int c = cq * 16 + i4 * 4 + j;
            base[c * 64 + ((dg ^ (c & 7)) << 3) + dl] = f2bf(vv[j]);
          }
        }
      }
    }
    __syncthreads();
#pragma unroll
    for (int nn = 0; nn < 2; nn++) {
      bf16x8 bf[4][2];
#pragma unroll
      for (int ci = 0; ci < 4; ci++) {
        const unsigned short* bp = wB + nn * 4096 + (ci * 16 + m) * 64;
#pragma unroll
        for (int kk = 0; kk < 2; kk++)
          bf[ci][kk] = *(const bf16x8*)&bp[((kk * 4 + q) ^ ms) << 3];
      }
      float ps[4] = {0.f, 0.f, 0.f, 0.f};
      const unsigned short* cf = cF2 + (w * 8 + np * 2 + nn) * 64 + q * 4;
#pragma unroll
      for (int mi = 0; mi < 4; mi++) {
        float cfv[4];
#pragma unroll
        for (int r = 0; r < 4; r++)
          cfv[r] = __uint_as_float((unsigned)cf[mi * 16 + r] << 16);
#pragma unroll
        for (int ci = 0; ci < 4; ci++) {
          floatx4 c0 = {0.f, 0.f, 0.f, 0.f};
          c0 = __builtin_amdgcn_mfma_f32_16x16x32_bf16(a[mi][0], bf[ci][0], c0, 0, 0, 0);
          c0 = __builtin_amdgcn_mfma_f32_16x16x32_bf16(a[mi][1], bf[ci][1], c0, 0, 0, 0);
#pragma unroll
          for (int r = 0; r < 4; r++) { float tv = c0[r]; ps[ci] += cfv[r] * tv * tv; }
        }
      }
#pragma unroll
      for (int ci = 0; ci < 4; ci++) {
        ps[ci] += __shfl_xor(ps[ci], 16, 64);
        ps[ci] += __shfl_xor(ps[ci], 32, 64);
      }
      if (q == 0) {
#pragma unroll
        for (int ci = 0; ci < 4; ci++)
          ssq[(b0 + w) * 2048 + (n0 + nn) * 64 + ci * 16 + m] = ps[ci];
      }
    }
  }
}

// ---------------------------------------------------------------------------
// k_prep: blocks 0..7: A_h = Wq_h . Wk_h^T. block 8: pair matrix K from kmf.
// ---------------------------------------------------------------------------
__global__ __launch_bounds__(256) void k_prep(
    const float* __restrict__ Wq, const float* __restrict__ Wk,
    const float* __restrict__ kmf, float* __restrict__ Ab, float* __restrict__ Kb)
{
  const int t = threadIdx.x;
  if (blockIdx.x < 8) {
    __shared__ __align__(16) float wkS[64 * 68];
    __shared__ __align__(16) float wqS[16 * 68];
    const int h = blockIdx.x & 1, rg = blockIdx.x >> 1;
#pragma unroll
    for (int k = 0; k < 4; k++) {
      int lin = t + 256 * k; int dp = lin >> 4; int e0 = (lin & 15) << 2;
      *(float4*)&wkS[lidx(dp, e0)] = *(const float4*)(Wk + dp * 128 + h * 64 + e0);
    }
    {
      int dl = t >> 4, e0 = (t & 15) << 2;
      *(float4*)&wqS[lidx(dl, e0)] = *(const float4*)(Wq + (rg * 16 + dl) * 128 + h * 64 + e0);
    }
    __syncthreads();
    const int dl = t >> 4, dp0 = (t & 15) << 2;
    float acc[4] = {};
    for (int e = 0; e < 64; e += 4) {
      float q4[4];
      *(float4*)q4 = *(const float4*)&wqS[lidx(dl, e)];
#pragma unroll
      for (int c = 0; c < 4; c++) {
        float mr[4];
        *(float4*)mr = *(const float4*)&wkS[lidx(dp0 + c, e)];
        acc[c] += q4[0] * mr[0] + q4[1] * mr[1] + q4[2] * mr[2] + q4[3] * mr[3];
      }
    }
    *(float4*)(Ab + h * 4096 + (rg * 16 + dl) * 64 + dp0) = *(float4*)acc;
  } else {
    __shared__ float Ks[1024];
    *(float4*)&Ks[t * 4] = make_float4(0.f, 0.f, 0.f, 0.f);
    __syncthreads();
    if (t < 248) {
#pragma unroll
      for (int j = 0; j < 2; j++) {
        int p = t * 2 + j;
        if (p < 496) {
          int l = 0, rem = p;
          while (rem >= 31 - l) { rem -= 31 - l; ++l; }
          int r = l + 1 + rem;
          float v = kmf[p];
          Ks[l * 32 + r] = v;
          Ks[r * 32 + l] = v;
        }
      }
    }
    __syncthreads();
    *(float4*)&Kb[t * 4] = *(const float4*)&Ks[t * 4];
  }
}

// ---------------------------------------------------------------------------
// k_attn: per-b fused attention + FM + MF + high_int. One block per b.
// fp32 only, 35.3 KB LDS -> 4 blocks/CU. Softmax 4 threads/row.
// ---------------------------------------------------------------------------
__global__ __launch_bounds__(256) void k_attn(
    const float* __restrict__ fwv, const float* __restrict__ ssq,
    const float* __restrict__ Ab, const float* __restrict__ Kb,
    const float* __restrict__ Wv, const float* __restrict__ Wr,
    const float* __restrict__ kfm, const float* __restrict__ bfm,
    const float* __restrict__ bmf, const float* __restrict__ khi,
    const float* __restrict__ bhi, float* __restrict__ out0)
{
  __shared__ __align__(16) float smem[8832];   // 35328 B
  float* fwS  = smem;               // 32x68 (2176 f)
  float* pS   = smem + 2176;        // 64x36 (2304 f) scores/probs; redH alias
  float* bufA = smem + 4480;        // 32x68 (2176 f) A-half
  float* tS   = smem + 6656;        // 32x68 (2176 f) T
  float* vS   = smem + 4480;        // 32x132 (4224 f) value matrix (alias)
  float* redH = smem + 2176;        // 16x132 (2112 f) (alias of pS)
  float* Kf   = smem + 4480;        // 32x32 (1024 f) (alias, post-vS)
  float* red1 = smem + 5504;        // 8x68 (544 f)

  const int b = blockIdx.x, t = threadIdx.x;
  const int tn = t >> 4, te = t & 15;
  const int n0 = tn * 2, e0 = te * 8, d0 = te * 4;

#pragma unroll
  for (int k = 0; k < 2; k++) {
    int lin = t + 256 * k; int nn = lin >> 4; int c0 = (lin & 15) << 2;
    *(float4*)&fwS[lidx(nn, c0)] = *(const float4*)(fwv + b * 2048 + nn * 64 + c0);
  }
  __syncthreads();

  // ---- scores: S_h = (fwS . A_h) . fwS^T ----------------------------------
  for (int h = 0; h < 2; h++) {
    float tacc[2][4] = {};
    for (int half = 0; half < 2; half++) {
#pragma unroll
      for (int k = 0; k < 2; k++) {
        int lin = t + 256 * k; int d = lin >> 4; int c0 = (lin & 15) << 2;
        *(float4*)&bufA[lidx(d, c0)] =
            *(const float4*)(Ab + h * 4096 + (half * 32 + d) * 64 + c0);
      }
      __syncthreads();
      for (int dq = 0; dq < 32; dq += 4) {
        float fw0[4], fw1[4];
        *(float4*)fw0 = *(const float4*)&fwS[lidx(n0, half * 32 + dq)];
        *(float4*)fw1 = *(const float4*)&fwS[lidx(n0 + 1, half * 32 + dq)];
#pragma unroll
        for (int j = 0; j < 4; j++) {
          float mr[4];
          *(float4*)mr = *(const float4*)&bufA[lidx(dq + j, d0)];
#pragma unroll
          for (int c = 0; c < 4; c++) {
            tacc[0][c] += fw0[j] * mr[c];
            tacc[1][c] += fw1[j] * mr[c];
          }
        }
      }
      __syncthreads();
    }
    *(float4*)&tS[lidx(n0, d0)] = *(float4*)tacc[0];
    *(float4*)&tS[lidx(n0 + 1, d0)] = *(float4*)tacc[1];
    __syncthreads();
    {
      const int m0 = te * 2;
      float s00 = 0.f, s01 = 0.f, s10 = 0.f, s11 = 0.f;
      for (int kk = 0; kk < 16; kk++) {
        float ta0[4], ta1[4], f0[4], f1[4];
        *(float4*)ta0 = *(const float4*)&tS[lidx(n0, kk * 4)];
        *(float4*)ta1 = *(const float4*)&tS[lidx(n0 + 1, kk * 4)];
        *(float4*)f0 = *(const float4*)&fwS[lidx(m0, kk * 4)];
        *(float4*)f1 = *(const float4*)&fwS[lidx(m0 + 1, kk * 4)];
#pragma unroll
        for (int j = 0; j < 4; j++) {
          s00 += ta0[j] * f0[j]; s01 += ta0[j] * f1[j];
          s10 += ta1[j] * f0[j]; s11 += ta1[j] * f1[j];
        }
      }
      pS[(h * 32 + n0) * 36 + m0] = s00;
      pS[(h * 32 + n0) * 36 + m0 + 1] = s01;
      pS[(h * 32 + n0 + 1) * 36 + m0] = s10;
      pS[(h * 32 + n0 + 1) * 36 + m0 + 1] = s11;
    }
    __syncthreads();
  }

  // ---- softmax over m per (h,n) row: 4 threads/row, shuffle reduce --------
  {
    const int r = t >> 2, sub = t & 3;
    const int base = r * 36 + sub * 8;
    float v0[4], v1[4];
    *(float4*)v0 = *(const float4*)&pS[base];
    *(float4*)v1 = *(const float4*)&pS[base + 4];
    float mx = fmaxf(fmaxf(fmaxf(v0[0], v0[1]), fmaxf(v0[2], v0[3])),
                     fmaxf(fmaxf(v1[0], v1[1]), fmaxf(v1[2], v1[3])));
    mx = fmaxf(mx, __shfl_xor(mx, 1, 64));
    mx = fmaxf(mx, __shfl_xor(mx, 2, 64));
    float sum = 0.f;
#pragma unroll
    for (int j = 0; j < 4; j++) { v0[j] = __expf(v0[j] - mx); sum += v0[j]; }
#pragma unroll
    for (int j = 0; j < 4; j++) { v1[j] = __expf(v1[j] - mx); sum += v1[j]; }
    sum += __shfl_xor(sum, 1, 64);
    sum += __shfl_xor(sum, 2, 64);
    const float inv = 1.0f / sum;
#pragma unroll
    for (int j = 0; j < 4; j++) { v0[j] *= inv; v1[j] *= inv; }
    *(float4*)&pS[base] = *(float4*)v0;
    *(float4*)&pS[base + 4] = *(float4*)v1;
  }
  __syncthreads();

  // ---- vS = fwS . Wv (Wv streamed from L2) --------------------------------
  {
    float acc[2][8] = {};
    for (int dq = 0; dq < 64; dq += 4) {
      float fw0[4], fw1[4];
      *(float4*)fw0 = *(const float4*)&fwS[lidx(n0, dq)];
      *(float4*)fw1 = *(const float4*)&fwS[lidx(n0 + 1, dq)];
#pragma unroll
      for (int jj = 0; jj < 4; jj++) {
        float w8[8];
        *(float4*)&w8[0] = *(const float4*)(Wv + (dq + jj) * 128 + e0);
        *(float4*)&w8[4] = *(const float4*)(Wv + (dq + jj) * 128 + e0 + 4);
#pragma unroll
        for (int j = 0; j < 8; j++) {
          acc[0][j] += fw0[jj] * w8[j];
          acc[1][j] += fw1[jj] * w8[j];
        }
      }
    }
    *(float4*)&vS[n0 * 132 + e0] = *(float4*)&acc[0][0];
    *(float4*)&vS[n0 * 132 + e0 + 4] = *(float4*)&acc[0][4];
    *(float4*)&vS[(n0 + 1) * 132 + e0] = *(float4*)&acc[1][0];
    *(float4*)&vS[(n0 + 1) * 132 + e0 + 4] = *(float4*)&acc[1][4];
  }
  __syncthreads();

  // ---- out = P.v + fwS.Wr, relu, khi-weighted reduce ----------------------
  {
    const int h2 = te >> 3;
    float pacc[2][8] = {};
    for (int m = 0; m < 32; m++) {
      float p0 = pS[(h2 * 32 + n0) * 36 + m];
      float p1 = pS[(h2 * 32 + n0 + 1) * 36 + m];
      float vr[8];
      *(float4*)&vr[0] = *(const float4*)&vS[m * 132 + e0];
      *(float4*)&vr[4] = *(const float4*)&vS[m * 132 + e0 + 4];
#pragma unroll
      for (int j = 0; j < 8; j++) {
        pacc[0][j] += p0 * vr[j];
        pacc[1][j] += p1 * vr[j];
      }
    }
    for (int dq = 0; dq < 64; dq += 4) {
      float fw0[4], fw1[4];
      *(float4*)fw0 = *(const float4*)&fwS[lidx(n0, dq)];
      *(float4*)fw1 = *(const float4*)&fwS[lidx(n0 + 1, dq)];
#pragma unroll
      for (int jj = 0; jj < 4; jj++) {
        float w8[8];
        *(float4*)&w8[0] = *(const float4*)(Wr + (dq + jj) * 128 + e0);
        *(float4*)&w8[4] = *(const float4*)(Wr + (dq + jj) * 128 + e0 + 4);
#pragma unroll
        for (int j = 0; j < 8; j++) {
          pacc[0][j] += fw0[jj] * w8[j];
          pacc[1][j] += fw1[jj] * w8[j];
        }
      }
    }
    __syncthreads();   // all pS/vS readers done; redH (pS) & Kf (vS) writes follow
    {
      float kh0 = khi[n0], kh1 = khi[n0 + 1];
      float ph[8];
#pragma unroll
      for (int j = 0; j < 8; j++)
        ph[j] = kh0 * fmaxf(pacc[0][j], 0.f) + kh1 * fmaxf(pacc[1][j], 0.f);
      *(float4*)&redH[tn * 132 + e0] = *(float4*)&ph[0];
      *(float4*)&redH[tn * 132 + e0 + 4] = *(float4*)&ph[4];
    }
  }
  *(float4*)&Kf[t * 4] = *(const float4*)(Kb + t * 4);
  __syncthreads();

  // ---- high_int out + FM/MF partials --------------------------------------
  if (t < 128) {
    float s = 0.f;
#pragma unroll
    for (int k = 0; k < 16; k++) s += redH[k * 132 + t];
    out0[b * 256 + 128 + t] = s + bhi[t];
  }
  {
    const int c = t & 63, nq = t >> 6;
    float p = 0.f;
#pragma unroll
    for (int k = 0; k < 8; k++) {
      int nn = nq * 8 + k;
      float fv = fwS[lidx(nn, c)];
      float sv = ssq[b * 2048 + nn * 64 + c];
      p += (fv * fv - sv) * kfm[nn];
    }
    red1[nq * 68 + c] = p;
    // MF: 0.5 * fw^T K fw column c; loop-inverted, K reads wave-uniform
    float inner[8] = {};
    for (int r = 0; r < 32; r++) {
      float fr = fwS[lidx(r, c)];
#pragma unroll
      for (int l8 = 0; l8 < 8; l8++)
        inner[l8] += Kf[(nq * 8 + l8) * 32 + r] * fr;
    }
    float hmf = 0.f;
#pragma unroll
    for (int l8 = 0; l8 < 8; l8++)
      hmf += fwS[lidx(nq * 8 + l8, c)] * inner[l8];
    red1[(4 + nq) * 68 + c] = hmf;
  }
  __syncthreads();
  if (t < 64) {
    out0[b * 256 + t] = red1[t] + red1[68 + t] + red1[136 + t] + red1[204 + t] + bfm[t];
    float h2 = red1[272 + t] + red1[340 + t] + red1[408 + t] + red1[476 + t];
    out0[b * 256 + 64 + t] = 0.5f * h2 + bmf[t];
  }
}

// ---------------------------------------------------------------------------
extern "C" void kernel_launch(void* const* d_in, const int* in_sizes, int n_in,
                              void* d_out, int out_size, void* d_ws, size_t ws_size,
                              hipStream_t stream) {
  (void)in_sizes; (void)n_in; (void)out_size; (void)ws_size;
  const float* x     = (const float*)d_in[0];
  const float* W     = (const float*)d_in[1];
  const float* rinit = (const float*)d_in[2];
  const float* kfm   = (const float*)d_in[3];
  const float* bfm   = (const float*)d_in[4];
  const float* kmf   = (const float*)d_in[5];
  const float* bmf   = (const float*)d_in[6];
  const float* khi   = (const float*)d_in[7];
  const float* bhi   = (const float*)d_in[8];
  const float* Wq    = (const float*)d_in[9];
  const float* Wk    = (const float*)d_in[10];
  const float* Wv    = (const float*)d_in[11];
  const float* Wr    = (const float*)d_in[12];

  float* out0 = (float*)d_out;
  float* rs   = out0 + 1024 * 256;  // routing_score [B,32,64,1]
  float* Qbuf = rs;                 // Q scratch (32*4096 f) in rs region; dead
                                    // before k_upd(3) overwrites with real rs

  float* ws   = (float*)d_ws;       // 24 MB
  float* xc   = ws;                 // [B,32,64]; A/K alias after k_fwv
  float* ow   = ws + 2097152;       // [B,32,64]; fwv aliases after k_upd(3)
  float* blog = ws + 2 * 2097152;   // [B,32,64]; ssq aliases after k_upd(3)
  float* fwv  = ow;
  float* ssq  = blog;
  float* Abuf = xc;                 // [2][64][64] = 8192 floats
  float* Kbuf = xc + 8192;          // [32][32]    = 1024 floats

  k_prepq<<<32, 256, 0, stream>>>(W, Qbuf);
  k_upd<<<1024, 256, 0, stream>>>(x, rinit, ow, blog, xc, rs, 0);
  for (int it = 1; it <= 3; it++) {
    k_sowq<<<1024, 256, 0, stream>>>(Qbuf, xc, ow);
    k_upd<<<1024, 256, 0, stream>>>(x, rinit, ow, blog, xc, rs, it);
  }
  k_fwv<<<1024, 256, 0, stream>>>(W, xc, fwv);
  k_prep<<<9, 256, 0, stream>>>(Wq, Wk, kmf, Abuf, Kbuf);
  k_ih<<<1024, 256, 0, stream>>>(x, W, rs, ssq);
  k_attn<<<1024, 256, 0, stream>>>(fwv, ssq, Abuf, Kbuf, Wv, Wr,
                                   kfm, bfm, bmf, khi, bhi, out0);
}

// Round 7
// 279.561 us; speedup vs baseline: 3.5966x; 1.0032x over previous
//
#include <hip/hip_runtime.h>

// CapsuleLayer fused pipeline, round 7.
//  - R6 LESSON: hipLaunchCooperativeKernel fails under this harness (graph
//    capture / co-residency validation) -> out0 never written. NO cooperative
//    launches.
//  - k_route2: routing made fully per-b (one block per b, no grid sync).
//    Logits/c/xc/ow live entirely in LDS (52.2 KB -> 3 blocks/CU); Q streamed
//    from L2 per sow phase (Q-trick, exact), W streamed once for fwv.
//    Eliminates ALL intermediate global traffic (xc/ow/blog gone) and
//    collapses 10 small launches into 1.
//  - k_prep2 merges Q-build + A-build + K-build (41 blocks).
//  - k_ih / k_attn unchanged from R5 (known-good).
//  - Pipeline: k_prep2 -> k_route2 -> k_ih -> k_attn (4 launches, was 12).

#define EPS_SQ 1e-7f

typedef __attribute__((ext_vector_type(8))) short bf16x8;
typedef __attribute__((ext_vector_type(4))) float floatx4;

__device__ __forceinline__ int lidx(int r, int c) {
  // 64-col fp32 tile, row stride 68 dwords, quad-swizzle
  return r * 68 + ((((c >> 2) ^ (r >> 2)) & 15) << 2) + (c & 3);
}
__device__ __forceinline__ unsigned short f2bf(float f) {
  unsigned u = __float_as_uint(f);
  u += 0x7FFFu + ((u >> 16) & 1u);   // RNE
  return (unsigned short)(u >> 16);
}

// ---------------------------------------------------------------------------
// k_prep2: bid<32: Q_n = M_n.M_n^T ; bid 32..39: A_h = Wq_h.Wk_h^T ;
//          bid 40: symmetric pair matrix K from kmf.
// ---------------------------------------------------------------------------
__global__ __launch_bounds__(256) void k_prep2(
    const float* __restrict__ W, const float* __restrict__ Wq,
    const float* __restrict__ Wk, const float* __restrict__ kmf,
    float* __restrict__ Qb, float* __restrict__ Ab, float* __restrict__ Kb)
{
  const int t = threadIdx.x;
  if (blockIdx.x < 32) {
    __shared__ __align__(16) float Mn[64 * 68];
    const int n = blockIdx.x;
#pragma unroll
    for (int k = 0; k < 4; k++) {
      int lin = t + 256 * k; int d = lin >> 4; int c0 = (lin & 15) << 2;
      *(float4*)&Mn[lidx(d, c0)] = *(const float4*)(W + d * 2048 + n * 64 + c0);
    }
    __syncthreads();
    const int d1 = (t >> 4) * 4, d2 = (t & 15) * 4;
    float acc[4][4] = {};
    for (int cq = 0; cq < 64; cq += 4) {
      float m1[4][4], m2[4][4];
#pragma unroll
      for (int i = 0; i < 4; i++) *(float4*)m1[i] = *(const float4*)&Mn[lidx(d1 + i, cq)];
#pragma unroll
      for (int j = 0; j < 4; j++) *(float4*)m2[j] = *(const float4*)&Mn[lidx(d2 + j, cq)];
#pragma unroll
      for (int i = 0; i < 4; i++)
#pragma unroll
        for (int j = 0; j < 4; j++) {
          float s = 0.f;
#pragma unroll
          for (int k = 0; k < 4; k++) s += m1[i][k] * m2[j][k];
          acc[i][j] += s;
        }
    }
#pragma unroll
    for (int i = 0; i < 4; i++)
      *(float4*)(Qb + n * 4096 + (d1 + i) * 64 + d2) = *(float4*)acc[i];
  } else if (blockIdx.x < 40) {
    __shared__ __align__(16) float wkS[64 * 68];
    __shared__ __align__(16) float wqS[16 * 68];
    const int hb = blockIdx.x - 32;
    const int h = hb & 1, rg = hb >> 1;
#pragma unroll
    for (int k = 0; k < 4; k++) {
      int lin = t + 256 * k; int dp = lin >> 4; int e0 = (lin & 15) << 2;
      *(float4*)&wkS[lidx(dp, e0)] = *(const float4*)(Wk + dp * 128 + h * 64 + e0);
    }
    {
      int dl = t >> 4, e0 = (t & 15) << 2;
      *(float4*)&wqS[lidx(dl, e0)] = *(const float4*)(Wq + (rg * 16 + dl) * 128 + h * 64 + e0);
    }
    __syncthreads();
    const int dl = t >> 4, dp0 = (t & 15) << 2;
    float acc[4] = {};
    for (int e = 0; e < 64; e += 4) {
      float q4[4];
      *(float4*)q4 = *(const float4*)&wqS[lidx(dl, e)];
#pragma unroll
      for (int c = 0; c < 4; c++) {
        float mr[4];
        *(float4*)mr = *(const float4*)&wkS[lidx(dp0 + c, e)];
        acc[c] += q4[0] * mr[0] + q4[1] * mr[1] + q4[2] * mr[2] + q4[3] * mr[3];
      }
    }
    *(float4*)(Ab + h * 4096 + (rg * 16 + dl) * 64 + dp0) = *(float4*)acc;
  } else {
    __shared__ float Ks[1024];
    *(float4*)&Ks[t * 4] = make_float4(0.f, 0.f, 0.f, 0.f);
    __syncthreads();
    if (t < 248) {
#pragma unroll
      for (int j = 0; j < 2; j++) {
        int p = t * 2 + j;
        if (p < 496) {
          int l = 0, rem = p;
          while (rem >= 31 - l) { rem -= 31 - l; ++l; }
          int r = l + 1 + rem;
          float v = kmf[p];
          Ks[l * 32 + r] = v;
          Ks[r * 32 + l] = v;
        }
      }
    }
    __syncthreads();
    *(float4*)&Kb[t * 4] = *(const float4*)&Ks[t * 4];
  }
}

// ---------------------------------------------------------------------------
// k_route2: full routing for one b per block. No global intermediates.
//   loop it=0..3: cS = softmax_n(bS); [it==3: write rs]; xcS = cS.xs;
//                 [it<3: owS = scale*(xcS.Q_n) (Q streamed); bS += xs.owS^T]
//   epilogue: fwv = xcS . W (W streamed).
// ---------------------------------------------------------------------------
__global__ __launch_bounds__(256) void k_route2(
    const float* __restrict__ x, const float* __restrict__ W,
    const float* __restrict__ rinit, const float* __restrict__ Qb,
    float* __restrict__ rs, float* __restrict__ fwv)
{
  __shared__ __align__(16) float xs[64 * 68];    // 17408 B
  __shared__ __align__(16) float bS[32 * 68];    // logits (persistent)
  __shared__ __align__(16) float cS[32 * 68];    // softmax
  __shared__ __align__(16) float xcS[32 * 68];
  __shared__ __align__(16) float owS[32 * 68];
  const int b = blockIdx.x, t = threadIdx.x;
  const int tn = t >> 4, tlo = t & 15;
  const int nq = t >> 3, sub = t & 7;            // sow/fwv mapping

#pragma unroll
  for (int k = 0; k < 4; k++) {
    int lin = t + 256 * k; int f = lin >> 4; int d0 = (lin & 15) << 2;
    *(float4*)&xs[lidx(f, d0)] = *(const float4*)(x + b * 4096 + f * 64 + d0);
  }
#pragma unroll
  for (int k = 0; k < 2; k++) {
    int lin = t + 256 * k; int n = lin >> 4; int f0 = (lin & 15) << 2;
    *(float4*)&bS[lidx(n, f0)] = *(const float4*)(rinit + n * 64 + f0);
  }
  __syncthreads();

  for (int it = 0; it < 4; it++) {
    // ---- cS = softmax over n per f column ---------------------------------
    {
      const int nl = t & 31, fg = t >> 5;
#pragma unroll
      for (int k = 0; k < 8; k++) {
        int f = fg * 8 + k;
        float v = bS[lidx(nl, f)];
        float m = v;
        for (int s = 16; s > 0; s >>= 1) m = fmaxf(m, __shfl_xor(m, s, 64));
        float e = __expf(v - m);
        float sum = e;
        for (int s = 16; s > 0; s >>= 1) sum += __shfl_xor(sum, s, 64);
        cS[lidx(nl, f)] = e / sum;
      }
    }
    __syncthreads();
    if (it == 3) {
#pragma unroll
      for (int k = 0; k < 8; k++) {
        int lin = t + 256 * k; int n = lin >> 6, f = lin & 63;
        rs[b * 2048 + n * 64 + f] = cS[lidx(n, f)];
      }
    }
    // ---- xcS = cS . xs ----------------------------------------------------
    {
      const int n0 = tn * 2, d0 = tlo * 4;
      float acc[2][4] = {{0, 0, 0, 0}, {0, 0, 0, 0}};
      for (int f = 0; f < 64; f++) {
        float c0v = cS[lidx(n0, f)];
        float c1v = cS[lidx(n0 + 1, f)];
        float xr[4];
        *(float4*)xr = *(const float4*)&xs[lidx(f, d0)];
#pragma unroll
        for (int i = 0; i < 4; i++) {
          acc[0][i] += c0v * xr[i];
          acc[1][i] += c1v * xr[i];
        }
      }
      *(float4*)&xcS[lidx(n0, d0)] = *(float4*)acc[0];
      *(float4*)&xcS[lidx(n0 + 1, d0)] = *(float4*)acc[1];
    }
    __syncthreads();
    if (it == 3) break;

    // ---- owS = scale * (xcS . Q_n), Q streamed from L2 --------------------
    {
      const float* Qn = Qb + nq * 4096 + sub * 8;
      float y[8] = {};
#pragma unroll 4
      for (int d1 = 0; d1 < 64; d1++) {
        float xv = xcS[lidx(nq, d1)];
        float4 qa = *(const float4*)(Qn + d1 * 64);
        float4 qb2 = *(const float4*)(Qn + d1 * 64 + 4);
        y[0] += xv * qa.x; y[1] += xv * qa.y; y[2] += xv * qa.z; y[3] += xv * qa.w;
        y[4] += xv * qb2.x; y[5] += xv * qb2.y; y[6] += xv * qb2.z; y[7] += xv * qb2.w;
      }
      float xa[4], xb2[4];
      *(float4*)xa = *(const float4*)&xcS[lidx(nq, sub * 8)];
      *(float4*)xb2 = *(const float4*)&xcS[lidx(nq, sub * 8 + 4)];
      float ps = y[0] * xa[0] + y[1] * xa[1] + y[2] * xa[2] + y[3] * xa[3]
               + y[4] * xb2[0] + y[5] * xb2[1] + y[6] * xb2[2] + y[7] * xb2[3];
      ps += __shfl_xor(ps, 1, 64);
      ps += __shfl_xor(ps, 2, 64);
      ps += __shfl_xor(ps, 4, 64);
      const float ss = ps + EPS_SQ;
      const float sc = sqrtf(ss) / (0.5f + ss);
      float o0[4] = {y[0] * sc, y[1] * sc, y[2] * sc, y[3] * sc};
      float o1[4] = {y[4] * sc, y[5] * sc, y[6] * sc, y[7] * sc};
      *(float4*)&owS[lidx(nq, sub * 8)] = *(float4*)o0;
      *(float4*)&owS[lidx(nq, sub * 8 + 4)] = *(float4*)o1;
    }
    __syncthreads();

    // ---- bS += xs . owS^T (delta-b) ---------------------------------------
    {
      const int n0 = tn * 2, f0 = tlo * 4;
      float acc[2][4] = {{0, 0, 0, 0}, {0, 0, 0, 0}};
      for (int dq = 0; dq < 64; dq += 4) {
        float o[2][4];
        *(float4*)o[0] = *(const float4*)&owS[lidx(n0, dq)];
        *(float4*)o[1] = *(const float4*)&owS[lidx(n0 + 1, dq)];
#pragma unroll
        for (int i = 0; i < 4; i++) {
          float xr[4];
          *(float4*)xr = *(const float4*)&xs[lidx(f0 + i, dq)];
#pragma unroll
          for (int k = 0; k < 4; k++) {
            acc[0][i] += o[0][k] * xr[k];
            acc[1][i] += o[1][k] * xr[k];
          }
        }
      }
#pragma unroll
      for (int j = 0; j < 2; j++) {
        float tmp[4];
        *(float4*)tmp = *(const float4*)&bS[lidx(n0 + j, f0)];
#pragma unroll
        for (int i = 0; i < 4; i++) tmp[i] += acc[j][i];
        *(float4*)&bS[lidx(n0 + j, f0)] = *(float4*)tmp;
      }
    }
    __syncthreads();
  }

  // ---- fwv = xcS . W (W streamed from L2) ---------------------------------
  {
    const float* Wn = W + nq * 64 + sub * 8;
    float a8[8] = {};
#pragma unroll 4
    for (int d = 0; d < 64; d++) {
      float xv = xcS[lidx(nq, d)];
      float4 wa = *(const float4*)(Wn + d * 2048);
      float4 wb = *(const float4*)(Wn + d * 2048 + 4);
      a8[0] += xv * wa.x; a8[1] += xv * wa.y; a8[2] += xv * wa.z; a8[3] += xv * wa.w;
      a8[4] += xv * wb.x; a8[5] += xv * wb.y; a8[6] += xv * wb.z; a8[7] += xv * wb.w;
    }
    float o0[4] = {a8[0], a8[1], a8[2], a8[3]};
    float o1[4] = {a8[4], a8[5], a8[6], a8[7]};
    *(float4*)(fwv + b * 2048 + nq * 64 + sub * 8) = *(float4*)o0;
    *(float4*)(fwv + b * 2048 + nq * 64 + sub * 8 + 4) = *(float4*)o1;
  }
}

// ---------------------------------------------------------------------------
// k_ih: ssq via bf16 MFMA. Block = 4 b's x 8 n's, grid 1024. (unchanged R5)
// ---------------------------------------------------------------------------
__global__ __launch_bounds__(256) void k_ih(
    const float* __restrict__ x, const float* __restrict__ W,
    const float* __restrict__ rs, float* __restrict__ ssq)
{
  __shared__ __align__(16) unsigned short xB[4 * 64 * 64];   // 32768 B
  __shared__ __align__(16) unsigned short wB[2 * 64 * 64];   // 16384 B
  __shared__ unsigned short cF2[4 * 8 * 64];                 // 4096 B
  const int n_oct = (blockIdx.x & 3) << 3, b0 = (blockIdx.x >> 2) * 4;
  const int t = threadIdx.x, w = t >> 6, lane = t & 63;

#pragma unroll
  for (int k = 0; k < 16; k++) {
    int ch = t + 256 * k;
    int bb = ch >> 10, rem = ch & 1023;
    int f = rem >> 4, fq = rem & 15;
    int dg = fq >> 1, half = fq & 1;
    float4 v = *(const float4*)(x + ((b0 + bb) * 64 + f) * 64 + fq * 4);
    unsigned p0 = f2bf(v.x) | ((unsigned)f2bf(v.y) << 16);
    unsigned p1 = f2bf(v.z) | ((unsigned)f2bf(v.w) << 16);
    *(uint2*)&xB[bb * 4096 + f * 64 + ((dg ^ (f & 7)) << 3) + half * 4] =
        make_uint2(p0, p1);
  }
#pragma unroll
  for (int nn = 0; nn < 8; nn++) {
    float v = rs[(b0 + w) * 2048 + (n_oct + nn) * 64 + lane];
    cF2[(w * 8 + nn) * 64 + lane] = f2bf(v * v);
  }
  __syncthreads();

  const int m = lane & 15, q = lane >> 4, ms = m & 7;
  bf16x8 a[4][2];
#pragma unroll
  for (int mi = 0; mi < 4; mi++) {
    const unsigned short* bp = xB + w * 4096 + (mi * 16 + m) * 64;
#pragma unroll
    for (int kk = 0; kk < 2; kk++)
      a[mi][kk] = *(const bf16x8*)&bp[((kk * 4 + q) ^ ms) << 3];
  }

  for (int np = 0; np < 4; np++) {
    const int n0 = n_oct + np * 2;
    __syncthreads();
    {
      int dd = t >> 2, cq = t & 3;
      int dg = dd >> 3, dl = dd & 7;
#pragma unroll
      for (int nn = 0; nn < 2; nn++) {
        const float* wp = W + dd * 2048 + (n0 + nn) * 64 + cq * 16;
        unsigned short* base = wB + nn * 4096;
#pragma unroll
        for (int i4 = 0; i4 < 4; i4++) {
          float4 v = *(const float4*)(wp + i4 * 4);
          float vv[4] = {v.x, v.y, v.z, v.w};
#pragma unroll
          for (int j = 0; j < 4; j++) {
            int c = cq * 16 + i4 * 4 + j;
            base[c * 64 + ((dg ^ (c & 7)) << 3) + dl] = f2bf(vv[j]);
          }
        }
      }
    }
    __syncthreads();
#pragma unroll
    for (int nn = 0; nn < 2; nn++) {
      bf16x8 bf[4][2];
#pragma unroll
      for (int ci = 0; ci < 4; ci++) {
        const unsigned short* bp = wB + nn * 4096 + (ci * 16 + m) * 64;
#pragma unroll
        for (int kk = 0; kk < 2; kk++)
          bf[ci][kk] = *(const bf16x8*)&bp[((kk * 4 + q) ^ ms) << 3];
      }
      float ps[4] = {0.f, 0.f, 0.f, 0.f};
      const unsigned short* cf = cF2 + (w * 8 + np * 2 + nn) * 64 + q * 4;
#pragma unroll
      for (int mi = 0; mi < 4; mi++) {
        float cfv[4];
#pragma unroll
        for (int r = 0; r < 4; r++)
          cfv[r] = __uint_as_float((unsigned)cf[mi * 16 + r] << 16);
#pragma unroll
        for (int ci = 0; ci < 4; ci++) {
          floatx4 c0 = {0.f, 0.f, 0.f, 0.f};
          c0 = __builtin_amdgcn_mfma_f32_16x16x32_bf16(a[mi][0], bf[ci][0], c0, 0, 0, 0);
          c0 = __builtin_amdgcn_mfma_f32_16x16x32_bf16(a[mi][1], bf[ci][1], c0, 0, 0, 0);
#pragma unroll
          for (int r = 0; r < 4; r++) { float tv = c0[r]; ps[ci] += cfv[r] * tv * tv; }
        }
      }
#pragma unroll
      for (int ci = 0; ci < 4; ci++) {
        ps[ci] += __shfl_xor(ps[ci], 16, 64);
        ps[ci] += __shfl_xor(ps[ci], 32, 64);
      }
      if (q == 0) {
#pragma unroll
        for (int ci = 0; ci < 4; ci++)
          ssq[(b0 + w) * 2048 + (n0 + nn) * 64 + ci * 16 + m] = ps[ci];
      }
    }
  }
}

// ---------------------------------------------------------------------------
// k_attn: per-b fused attention + FM + MF + high_int. (unchanged R5)
// ---------------------------------------------------------------------------
__global__ __launch_bounds__(256) void k_attn(
    const float* __restrict__ fwv, const float* __restrict__ ssq,
    const float* __restrict__ Ab, const float* __restrict__ Kb,
    const float* __restrict__ Wv, const float* __restrict__ Wr,
    const float* __restrict__ kfm, const float* __restrict__ bfm,
    const float* __restrict__ bmf, const float* __restrict__ khi,
    const float* __restrict__ bhi, float* __restrict__ out0)
{
  __shared__ __align__(16) float smem[8832];   // 35328 B
  float* fwS  = smem;               // 32x68 (2176 f)
  float* pS   = smem + 2176;        // 64x36 (2304 f)
  float* bufA = smem + 4480;        // 32x68 (2176 f)
  float* tS   = smem + 6656;        // 32x68 (2176 f)
  float* vS   = smem + 4480;        // 32x132 (4224 f) (alias)
  float* redH = smem + 2176;        // 16x132 (alias of pS)
  float* Kf   = smem + 4480;        // 32x32 (alias, post-vS)
  float* red1 = smem + 5504;        // 8x68

  const int b = blockIdx.x, t = threadIdx.x;
  const int tn = t >> 4, te = t & 15;
  const int n0 = tn * 2, e0 = te * 8, d0 = te * 4;

#pragma unroll
  for (int k = 0; k < 2; k++) {
    int lin = t + 256 * k; int nn = lin >> 4; int c0 = (lin & 15) << 2;
    *(float4*)&fwS[lidx(nn, c0)] = *(const float4*)(fwv + b * 2048 + nn * 64 + c0);
  }
  __syncthreads();

  for (int h = 0; h < 2; h++) {
    float tacc[2][4] = {};
    for (int half = 0; half < 2; half++) {
#pragma unroll
      for (int k = 0; k < 2; k++) {
        int lin = t + 256 * k; int d = lin >> 4; int c0 = (lin & 15) << 2;
        *(float4*)&bufA[lidx(d, c0)] =
            *(const float4*)(Ab + h * 4096 + (half * 32 + d) * 64 + c0);
      }
      __syncthreads();
      for (int dq = 0; dq < 32; dq += 4) {
        float fw0[4], fw1[4];
        *(float4*)fw0 = *(const float4*)&fwS[lidx(n0, half * 32 + dq)];
        *(float4*)fw1 = *(const float4*)&fwS[lidx(n0 + 1, half * 32 + dq)];
#pragma unroll
        for (int j = 0; j < 4; j++) {
          float mr[4];
          *(float4*)mr = *(const float4*)&bufA[lidx(dq + j, d0)];
#pragma unroll
          for (int c = 0; c < 4; c++) {
            tacc[0][c] += fw0[j] * mr[c];
            tacc[1][c] += fw1[j] * mr[c];
          }
        }
      }
      __syncthreads();
    }
    *(float4*)&tS[lidx(n0, d0)] = *(float4*)tacc[0];
    *(float4*)&tS[lidx(n0 + 1, d0)] = *(float4*)tacc[1];
    __syncthreads();
    {
      const int m0 = te * 2;
      float s00 = 0.f, s01 = 0.f, s10 = 0.f, s11 = 0.f;
      for (int kk = 0; kk < 16; kk++) {
        float ta0[4], ta1[4], f0[4], f1[4];
        *(float4*)ta0 = *(const float4*)&tS[lidx(n0, kk * 4)];
        *(float4*)ta1 = *(const float4*)&tS[lidx(n0 + 1, kk * 4)];
        *(float4*)f0 = *(const float4*)&fwS[lidx(m0, kk * 4)];
        *(float4*)f1 = *(const float4*)&fwS[lidx(m0 + 1, kk * 4)];
#pragma unroll
        for (int j = 0; j < 4; j++) {
          s00 += ta0[j] * f0[j]; s01 += ta0[j] * f1[j];
          s10 += ta1[j] * f0[j]; s11 += ta1[j] * f1[j];
        }
      }
      pS[(h * 32 + n0) * 36 + m0] = s00;
      pS[(h * 32 + n0) * 36 + m0 + 1] = s01;
      pS[(h * 32 + n0 + 1) * 36 + m0] = s10;
      pS[(h * 32 + n0 + 1) * 36 + m0 + 1] = s11;
    }
    __syncthreads();
  }

  {
    const int r = t >> 2, sub = t & 3;
    const int base = r * 36 + sub * 8;
    float v0[4], v1[4];
    *(float4*)v0 = *(const float4*)&pS[base];
    *(float4*)v1 = *(const float4*)&pS[base + 4];
    float mx = fmaxf(fmaxf(fmaxf(v0[0], v0[1]), fmaxf(v0[2], v0[3])),
                     fmaxf(fmaxf(v1[0], v1[1]), fmaxf(v1[2], v1[3])));
    mx = fmaxf(mx, __shfl_xor(mx, 1, 64));
    mx = fmaxf(mx, __shfl_xor(mx, 2, 64));
    float sum = 0.f;
#pragma unroll
    for (int j = 0; j < 4; j++) { v0[j] = __expf(v0[j] - mx); sum += v0[j]; }
#pragma unroll
    for (int j = 0; j < 4; j++) { v1[j] = __expf(v1[j] - mx); sum += v1[j]; }
    sum += __shfl_xor(sum, 1, 64);
    sum += __shfl_xor(sum, 2, 64);
    const float inv = 1.0f / sum;
#pragma unroll
    for (int j = 0; j < 4; j++) { v0[j] *= inv; v1[j] *= inv; }
    *(float4*)&pS[base] = *(float4*)v0;
    *(float4*)&pS[base + 4] = *(float4*)v1;
  }
  __syncthreads();

  {
    float acc[2][8] = {};
    for (int dq = 0; dq < 64; dq += 4) {
      float fw0[4], fw1[4];
      *(float4*)fw0 = *(const float4*)&fwS[lidx(n0, dq)];
      *(float4*)fw1 = *(const float4*)&fwS[lidx(n0 + 1, dq)];
#pragma unroll
      for (int jj = 0; jj < 4; jj++) {
        float w8[8];
        *(float4*)&w8[0] = *(const float4*)(Wv + (dq + jj) * 128 + e0);
        *(float4*)&w8[4] = *(const float4*)(Wv + (dq + jj) * 128 + e0 + 4);
#pragma unroll
        for (int j = 0; j < 8; j++) {
          acc[0][j] += fw0[jj] * w8[j];
          acc[1][j] += fw1[jj] * w8[j];
        }
      }
    }
    *(float4*)&vS[n0 * 132 + e0] = *(float4*)&acc[0][0];
    *(float4*)&vS[n0 * 132 + e0 + 4] = *(float4*)&acc[0][4];
    *(float4*)&vS[(n0 + 1) * 132 + e0] = *(float4*)&acc[1][0];
    *(float4*)&vS[(n0 + 1) * 132 + e0 + 4] = *(float4*)&acc[1][4];
  }
  __syncthreads();

  {
    const int h2 = te >> 3;
    float pacc[2][8] = {};
    for (int m = 0; m < 32; m++) {
      float p0 = pS[(h2 * 32 + n0) * 36 + m];
      float p1 = pS[(h2 * 32 + n0 + 1) * 36 + m];
      float vr[8];
      *(float4*)&vr[0] = *(const float4*)&vS[m * 132 + e0];
      *(float4*)&vr[4] = *(const float4*)&vS[m * 132 + e0 + 4];
#pragma unroll
      for (int j = 0; j < 8; j++) {
        pacc[0][j] += p0 * vr[j];
        pacc[1][j] += p1 * vr[j];
      }
    }
    for (int dq = 0; dq < 64; dq += 4) {
      float fw0[4], fw1[4];
      *(float4*)fw0 = *(const float4*)&fwS[lidx(n0, dq)];
      *(float4*)fw1 = *(const float4*)&fwS[lidx(n0 + 1, dq)];
#pragma unroll
      for (int jj = 0; jj < 4; jj++) {
        float w8[8];
        *(float4*)&w8[0] = *(const float4*)(Wr + (dq + jj) * 128 + e0);
        *(float4*)&w8[4] = *(const float4*)(Wr + (dq + jj) * 128 + e0 + 4);
#pragma unroll
        for (int j = 0; j < 8; j++) {
          pacc[0][j] += fw0[jj] * w8[j];
          pacc[1][j] += fw1[jj] * w8[j];
        }
      }
    }
    __syncthreads();
    {
      float kh0 = khi[n0], kh1 = khi[n0 + 1];
      float ph[8];
#pragma unroll
      for (int j = 0; j < 8; j++)
        ph[j] = kh0 * fmaxf(pacc[0][j], 0.f) + kh1 * fmaxf(pacc[1][j], 0.f);
      *(float4*)&redH[tn * 132 + e0] = *(float4*)&ph[0];
      *(float4*)&redH[tn * 132 + e0 + 4] = *(float4*)&ph[4];
    }
  }
  *(float4*)&Kf[t * 4] = *(const float4*)(Kb + t * 4);
  __syncthreads();

  if (t < 128) {
    float s = 0.f;
#pragma unroll
    for (int k = 0; k < 16; k++) s += redH[k * 132 + t];
    out0[b * 256 + 128 + t] = s + bhi[t];
  }
  {
    const int c = t & 63, nq = t >> 6;
    float p = 0.f;
#pragma unroll
    for (int k = 0; k < 8; k++) {
      int nn = nq * 8 + k;
      float fv = fwS[lidx(nn, c)];
      float sv = ssq[b * 2048 + nn * 64 + c];
      p += (fv * fv - sv) * kfm[nn];
    }
    red1[nq * 68 + c] = p;
    float inner[8] = {};
    for (int r = 0; r < 32; r++) {
      float fr = fwS[lidx(r, c)];
#pragma unroll
      for (int l8 = 0; l8 < 8; l8++)
        inner[l8] += Kf[(nq * 8 + l8) * 32 + r] * fr;
    }
    float hmf = 0.f;
#pragma unroll
    for (int l8 = 0; l8 < 8; l8++)
      hmf += fwS[lidx(nq * 8 + l8, c)] * inner[l8];
    red1[(4 + nq) * 68 + c] = hmf;
  }
  __syncthreads();
  if (t < 64) {
    out0[b * 256 + t] = red1[t] + red1[68 + t] + red1[136 + t] + red1[204 + t] + bfm[t];
    float h2 = red1[272 + t] + red1[340 + t] + red1[408 + t] + red1[476 + t];
    out0[b * 256 + 64 + t] = 0.5f * h2 + bmf[t];
  }
}

// ---------------------------------------------------------------------------
extern "C" void kernel_launch(void* const* d_in, const int* in_sizes, int n_in,
                              void* d_out, int out_size, void* d_ws, size_t ws_size,
                              hipStream_t stream) {
  (void)in_sizes; (void)n_in; (void)out_size; (void)ws_size;
  const float* x     = (const float*)d_in[0];
  const float* W     = (const float*)d_in[1];
  const float* rinit = (const float*)d_in[2];
  const float* kfm   = (const float*)d_in[3];
  const float* bfm   = (const float*)d_in[4];
  const float* kmf   = (const float*)d_in[5];
  const float* bmf   = (const float*)d_in[6];
  const float* khi   = (const float*)d_in[7];
  const float* bhi   = (const float*)d_in[8];
  const float* Wq    = (const float*)d_in[9];
  const float* Wk    = (const float*)d_in[10];
  const float* Wv    = (const float*)d_in[11];
  const float* Wr    = (const float*)d_in[12];

  float* out0 = (float*)d_out;
  float* rs   = out0 + 1024 * 256;  // routing_score [B,32,64,1]

  float* ws   = (float*)d_ws;       // 24 MB
  float* Abuf = ws;                 // [2][64][64] = 8192 f
  float* Kbuf = ws + 8192;          // [32][32]    = 1024 f
  float* Qbuf = ws + 16384;         // [32][64][64] = 131072 f
  float* fwv  = ws + 2097152;       // [B,32,64]
  float* ssq  = ws + 2 * 2097152;   // [B,32,64]

  k_prep2<<<41, 256, 0, stream>>>(W, Wq, Wk, kmf, Qbuf, Abuf, Kbuf);
  k_route2<<<1024, 256, 0, stream>>>(x, W, rinit, Qbuf, rs, fwv);
  k_ih<<<1024, 256, 0, stream>>>(x, W, rs, ssq);
  k_attn<<<1024, 256, 0, stream>>>(fwv, ssq, Abuf, Kbuf, Wv, Wr,
                                   kfm, bfm, bmf, khi, bhi, out0);
}